// Round 3
// baseline (933.383 us; speedup 1.0000x reference)
//
#include <hip/hip_runtime.h>
#include <hip/hip_bf16.h>
#include <math.h>

#define N_NODES 100000
#define N_EDGES 1000000
#define ETOT    (N_EDGES + N_NODES)

constexpr float NEG_SLOPE = 0.2f;

// ---------------------------------------------------------------------------
// CSR build
// ---------------------------------------------------------------------------
__global__ void count_kernel(const int* __restrict__ ei, int* __restrict__ counts) {
    int i = blockIdx.x * blockDim.x + threadIdx.x;
    if (i >= ETOT) return;
    int dst = (i < N_EDGES) ? ei[N_EDGES + i] : (i - N_EDGES);
    atomicAdd(&counts[dst], 1);
}

__global__ __launch_bounds__(256) void block_sum_kernel(const int* __restrict__ counts,
                                                        int* __restrict__ blockSums, int n) {
    int b = blockIdx.x, t = threadIdx.x;
    int base = b * 1024 + t * 4;
    int s = 0;
    if (base + 3 < n) {
        int4 v = *reinterpret_cast<const int4*>(counts + base);
        s = v.x + v.y + v.z + v.w;
    } else {
        for (int i = 0; i < 4; i++) if (base + i < n) s += counts[base + i];
    }
    #pragma unroll
    for (int off = 32; off > 0; off >>= 1) s += __shfl_down(s, off);
    __shared__ int wsum[4];
    int lane = t & 63, wv = t >> 6;
    if (lane == 0) wsum[wv] = s;
    __syncthreads();
    if (t == 0) blockSums[b] = wsum[0] + wsum[1] + wsum[2] + wsum[3];
}

__global__ __launch_bounds__(256) void scan_sums_kernel(const int* __restrict__ blockSums,
                                                        int* __restrict__ blockBase, int nb) {
    __shared__ int sh[256];
    int t = threadIdx.x;
    int v = (t < nb) ? blockSums[t] : 0;
    sh[t] = v;
    __syncthreads();
    for (int off = 1; off < 256; off <<= 1) {
        int u = (t >= off) ? sh[t - off] : 0;
        __syncthreads();
        sh[t] += u;
        __syncthreads();
    }
    if (t < nb) blockBase[t] = sh[t] - v;
}

__global__ __launch_bounds__(256) void scan_final_kernel(const int* __restrict__ counts,
                                                         const int* __restrict__ blockBase,
                                                         int* __restrict__ offsets,
                                                         int* __restrict__ cursor, int n) {
    int b = blockIdx.x, t = threadIdx.x;
    int base = b * 1024 + t * 4;
    int c[4] = {0, 0, 0, 0};
    if (base + 3 < n) {
        int4 v = *reinterpret_cast<const int4*>(counts + base);
        c[0] = v.x; c[1] = v.y; c[2] = v.z; c[3] = v.w;
    } else {
        for (int i = 0; i < 4; i++) if (base + i < n) c[i] = counts[base + i];
    }
    int tsum = c[0] + c[1] + c[2] + c[3];
    int x = tsum;
    int lane = t & 63, wv = t >> 6;
    #pragma unroll
    for (int off = 1; off < 64; off <<= 1) {
        int u = __shfl_up(x, off);
        if (lane >= off) x += u;
    }
    __shared__ int wsum[4];
    if (lane == 63) wsum[wv] = x;
    __syncthreads();
    int wbase = 0;
    for (int w = 0; w < wv; w++) wbase += wsum[w];
    int run = blockBase[b] + wbase + (x - tsum);
    for (int i = 0; i < 4; i++) {
        if (base + i < n) { offsets[base + i] = run; cursor[base + i] = run; run += c[i]; }
    }
    if (b == 0 && t == 0) offsets[n] = ETOT;
}

__global__ void scatter_kernel(const int* __restrict__ ei, int* __restrict__ cursor,
                               int* __restrict__ csr_src) {
    int i = blockIdx.x * blockDim.x + threadIdx.x;
    if (i >= ETOT) return;
    int src, dst;
    if (i < N_EDGES) { src = ei[i]; dst = ei[N_EDGES + i]; }
    else             { src = dst = i - N_EDGES; }
    int pos = atomicAdd(&cursor[dst], 1);
    csr_src[pos] = src;
}

// ---------------------------------------------------------------------------
// GEMM: Hout[n][j] = sum_k X[n][k] * W[k][j]   (K fixed at 128), float4 k-loop
// ---------------------------------------------------------------------------
template <int OUT>
__global__ __launch_bounds__(256) void gemm_kernel(const float* __restrict__ X,
                                                   const float* __restrict__ W,
                                                   float* __restrict__ Hout) {
    constexpr int NODES  = 16;
    constexpr int GROUPS = 256 / OUT;
    constexpr int NPG    = NODES / GROUPS;
    __shared__ float xs[NODES * 128];
    const int t = threadIdx.x;
    const int j = t % OUT;
    const int g = t / OUT;
    const int nodeBase = blockIdx.x * NODES;

    const float4* Xs4 = reinterpret_cast<const float4*>(X + (size_t)nodeBase * 128);
    float4* xs4w = reinterpret_cast<float4*>(xs);
    #pragma unroll
    for (int idx = t; idx < NODES * 128 / 4; idx += 256)
        xs4w[idx] = Xs4[idx];
    __syncthreads();

    float acc[NPG] = {};
    const float4* xg4 = reinterpret_cast<const float4*>(&xs[g * NPG * 128]);
    #pragma unroll 8
    for (int k4 = 0; k4 < 32; k4++) {
        float w0 = W[(4 * k4 + 0) * OUT + j];
        float w1 = W[(4 * k4 + 1) * OUT + j];
        float w2 = W[(4 * k4 + 2) * OUT + j];
        float w3 = W[(4 * k4 + 3) * OUT + j];
        #pragma unroll
        for (int q = 0; q < NPG; q++) {
            float4 xv = xg4[q * 32 + k4];
            acc[q] += xv.x * w0;
            acc[q] += xv.y * w1;
            acc[q] += xv.z * w2;
            acc[q] += xv.w * w3;
        }
    }
    #pragma unroll
    for (int q = 0; q < NPG; q++)
        Hout[(size_t)(nodeBase + g * NPG + q) * OUT + j] = acc[q];
}

// ---------------------------------------------------------------------------
// Attention logits
// ---------------------------------------------------------------------------
template <int H, int CP>
__global__ __launch_bounds__(256) void al_kernel(const float* __restrict__ Hf,
                                                 const float* __restrict__ a_s,
                                                 const float* __restrict__ a_d,
                                                 float* __restrict__ alS,
                                                 float* __restrict__ alD, int n) {
    constexpr int CT  = H * CP;
    constexpr int GPB = 256 / CP;
    int gid = blockIdx.x * GPB + threadIdx.x / CP;
    int c   = threadIdx.x % CP;
    if (gid >= n * H) return;
    int node = gid / H, h = gid % H;
    float v  = Hf[(size_t)node * CT + h * CP + c];
    float vs = v * a_s[h * CP + c];
    float vd = v * a_d[h * CP + c];
    #pragma unroll
    for (int off = CP / 2; off > 0; off >>= 1) {
        vs += __shfl_down(vs, off, CP);
        vd += __shfl_down(vd, off, CP);
    }
    if (c == 0) { alS[gid] = vs; alD[gid] = vd; }
}

// ---------------------------------------------------------------------------
// Softmax: one wave per node, lanes over edges. Computes per-(node,head)
// max+denom (butterfly (m,d) merge), writes per-edge weights w[i,h]=exp(e-m)
// and per-node rdenom = 1/(d+1e-16).
// ---------------------------------------------------------------------------
template <int H>
__global__ __launch_bounds__(256) void softmax_kernel(const float* __restrict__ alS,
                                                      const float* __restrict__ alD,
                                                      const int* __restrict__ offs,
                                                      const int* __restrict__ csr,
                                                      float* __restrict__ wgt,
                                                      float* __restrict__ rden, int n) {
    int wave = (blockIdx.x * blockDim.x + threadIdx.x) >> 6;
    int lane = threadIdx.x & 63;
    if (wave >= n) return;
    const int node = wave;
    const int s0 = offs[node], s1 = offs[node + 1];

    float ald[H], m[H], d[H];
    #pragma unroll
    for (int h = 0; h < H; h++) {
        ald[h] = alD[node * H + h];
        m[h] = -1e30f;          // finite sentinel: avoids NaN in empty-lane merge
        d[h] = 0.0f;
    }

    for (int i = s0 + lane; i < s1; i += 64) {
        int s = csr[i];
        #pragma unroll
        for (int h = 0; h < H; h++) {
            float e = alS[s * H + h] + ald[h];
            e = (e > 0.0f) ? e : NEG_SLOPE * e;
            float nm = fmaxf(m[h], e);
            d[h] = d[h] * __expf(m[h] - nm) + __expf(e - nm);
            m[h] = nm;
        }
    }
    // butterfly merge of (m,d) across 64 lanes
    #pragma unroll
    for (int off = 32; off > 0; off >>= 1) {
        #pragma unroll
        for (int h = 0; h < H; h++) {
            float mo = __shfl_xor(m[h], off);
            float dd = __shfl_xor(d[h], off);
            float nm = fmaxf(m[h], mo);
            d[h] = d[h] * __expf(m[h] - nm) + dd * __expf(mo - nm);
            m[h] = nm;
        }
    }
    // second pass: per-edge weights
    for (int i = s0 + lane; i < s1; i += 64) {
        int s = csr[i];
        #pragma unroll
        for (int h = 0; h < H; h++) {
            float e = alS[s * H + h] + ald[h];
            e = (e > 0.0f) ? e : NEG_SLOPE * e;
            wgt[i * H + h] = __expf(e - m[h]);
        }
    }
    if (lane == 0) {
        #pragma unroll
        for (int h = 0; h < H; h++)
            rden[node * H + h] = 1.0f / (d[h] + 1e-16f);
    }
}

// ---------------------------------------------------------------------------
// Lean aggregation: acc[ch] += w[i,h] * Hf[s,ch]; epilogue applies rdenom,
// bias, optional ELU. 2-edge manual unroll for load overlap.
// ---------------------------------------------------------------------------
template <int CT, int H, bool DO_ELU>
__global__ __launch_bounds__(256) void agg2_kernel(const float* __restrict__ Hf,
                                                   const float* __restrict__ wgt,
                                                   const float* __restrict__ rden,
                                                   const float* __restrict__ bias,
                                                   const int* __restrict__ offs,
                                                   const int* __restrict__ csr,
                                                   float* __restrict__ out, int n) {
    constexpr int CPL = CT / 64;
    constexpr int CP  = CT / H;
    int wave = (blockIdx.x * blockDim.x + threadIdx.x) >> 6;
    int lane = threadIdx.x & 63;
    if (wave >= n) return;
    const int node = wave;

    int hh[CPL];
    float acc[CPL];
    #pragma unroll
    for (int q = 0; q < CPL; q++) { hh[q] = (lane + q * 64) / CP; acc[q] = 0.0f; }

    const int s0 = offs[node], s1 = offs[node + 1];
    int i = s0;
    for (; i + 1 < s1; i += 2) {
        int sa = csr[i], sb = csr[i + 1];
        float wa[CPL], wb[CPL], ha[CPL], hb[CPL];
        #pragma unroll
        for (int q = 0; q < CPL; q++) {
            wa[q] = wgt[i * H + hh[q]];
            wb[q] = wgt[(i + 1) * H + hh[q]];
            ha[q] = Hf[(size_t)sa * CT + lane + q * 64];
            hb[q] = Hf[(size_t)sb * CT + lane + q * 64];
        }
        #pragma unroll
        for (int q = 0; q < CPL; q++) acc[q] += wa[q] * ha[q];
        #pragma unroll
        for (int q = 0; q < CPL; q++) acc[q] += wb[q] * hb[q];
    }
    if (i < s1) {
        int sa = csr[i];
        #pragma unroll
        for (int q = 0; q < CPL; q++)
            acc[q] += wgt[i * H + hh[q]] * Hf[(size_t)sa * CT + lane + q * 64];
    }

    #pragma unroll
    for (int q = 0; q < CPL; q++) {
        int ch  = lane + q * 64;
        float o = acc[q] * rden[node * H + hh[q]] + bias[ch];
        if (DO_ELU) o = (o > 0.0f) ? o : expm1f(o);
        out[(size_t)node * CT + ch] = o;
    }
}

// ---------------------------------------------------------------------------
extern "C" void kernel_launch(void* const* d_in, const int* in_sizes, int n_in,
                              void* d_out, int out_size, void* d_ws, size_t ws_size,
                              hipStream_t stream) {
    const float* x   = (const float*)d_in[0];
    const int*   ei  = (const int*)d_in[1];
    const float* W0  = (const float*)d_in[2];
    const float* as0 = (const float*)d_in[3];
    const float* ad0 = (const float*)d_in[4];
    const float* b0  = (const float*)d_in[5];
    const float* W1  = (const float*)d_in[6];
    const float* as1 = (const float*)d_in[7];
    const float* ad1 = (const float*)d_in[8];
    const float* b1  = (const float*)d_in[9];
    const float* W2  = (const float*)d_in[10];
    const float* as2 = (const float*)d_in[11];
    const float* ad2 = (const float*)d_in[12];
    const float* b2  = (const float*)d_in[13];

    char* ws = (char*)d_ws;
    size_t off = 0;
    auto alloc = [&](size_t bytes) -> void* {
        void* p = ws + off;
        off += (bytes + 255) & ~size_t(255);
        return p;
    };
    float* B0      = (float*)alloc((size_t)N_NODES * 128 * sizeof(float));
    float* B1      = (float*)alloc((size_t)N_NODES * 128 * sizeof(float));
    float* alS     = (float*)alloc((size_t)N_NODES * 4 * sizeof(float));
    float* alD     = (float*)alloc((size_t)N_NODES * 4 * sizeof(float));
    float* wgt     = (float*)alloc((size_t)ETOT * 4 * sizeof(float));
    float* rden    = (float*)alloc((size_t)N_NODES * 4 * sizeof(float));
    int*   counts  = (int*)alloc((size_t)N_NODES * sizeof(int));
    int*   offs    = (int*)alloc((size_t)(N_NODES + 1) * sizeof(int));
    int*   cursor  = (int*)alloc((size_t)N_NODES * sizeof(int));
    int*   csr     = (int*)alloc((size_t)ETOT * sizeof(int));
    int*   bsums   = (int*)alloc(256 * sizeof(int));
    int*   bbase   = (int*)alloc(256 * sizeof(int));

    const int NB = (N_NODES + 1023) / 1024;

    // ---- CSR build ----
    hipMemsetAsync(counts, 0, (size_t)N_NODES * sizeof(int), stream);
    count_kernel<<<(ETOT + 255) / 256, 256, 0, stream>>>(ei, counts);
    block_sum_kernel<<<NB, 256, 0, stream>>>(counts, bsums, N_NODES);
    scan_sums_kernel<<<1, 256, 0, stream>>>(bsums, bbase, NB);
    scan_final_kernel<<<NB, 256, 0, stream>>>(counts, bbase, offs, cursor, N_NODES);
    scatter_kernel<<<(ETOT + 255) / 256, 256, 0, stream>>>(ei, cursor, csr);

    const int GEMM_GRID = N_NODES / 16;
    const int NODE_WAVE_GRID = (N_NODES + 3) / 4;   // 4 waves/block

    // ---- layer 0 ----
    gemm_kernel<128><<<GEMM_GRID, 256, 0, stream>>>(x, W0, B0);
    al_kernel<4, 32><<<(N_NODES * 4 + 7) / 8, 256, 0, stream>>>(B0, as0, ad0, alS, alD, N_NODES);
    softmax_kernel<4><<<NODE_WAVE_GRID, 256, 0, stream>>>(alS, alD, offs, csr, wgt, rden, N_NODES);
    agg2_kernel<128, 4, true><<<NODE_WAVE_GRID, 256, 0, stream>>>(B0, wgt, rden, b0, offs, csr, B1, N_NODES);

    // ---- layer 1 ----
    gemm_kernel<128><<<GEMM_GRID, 256, 0, stream>>>(B1, W1, B0);
    al_kernel<4, 32><<<(N_NODES * 4 + 7) / 8, 256, 0, stream>>>(B0, as1, ad1, alS, alD, N_NODES);
    softmax_kernel<4><<<NODE_WAVE_GRID, 256, 0, stream>>>(alS, alD, offs, csr, wgt, rden, N_NODES);
    agg2_kernel<128, 4, true><<<NODE_WAVE_GRID, 256, 0, stream>>>(B0, wgt, rden, b1, offs, csr, B1, N_NODES);

    // ---- layer 2 ----
    gemm_kernel<64><<<GEMM_GRID, 256, 0, stream>>>(B1, W2, B0);
    al_kernel<1, 64><<<(N_NODES + 3) / 4, 256, 0, stream>>>(B0, as2, ad2, alS, alD, N_NODES);
    softmax_kernel<1><<<NODE_WAVE_GRID, 256, 0, stream>>>(alS, alD, offs, csr, wgt, rden, N_NODES);
    agg2_kernel<64, 1, false><<<NODE_WAVE_GRID, 256, 0, stream>>>(B0, wgt, rden, b2, offs, csr,
                                                                  (float*)d_out, N_NODES);
}

// Round 4
// 731.731 us; speedup vs baseline: 1.2756x; 1.2756x over previous
//
#include <hip/hip_runtime.h>
#include <hip/hip_bf16.h>
#include <math.h>

#define N_NODES 100000
#define N_EDGES 1000000
#define ETOT    (N_EDGES + N_NODES)

constexpr float NEG_SLOPE = 0.2f;

typedef short short8 __attribute__((ext_vector_type(8)));
typedef float f32x4  __attribute__((ext_vector_type(4)));
typedef unsigned short ushort_t;
typedef unsigned int uint_t;

__device__ __forceinline__ ushort_t f2bf(float f) {
    uint_t u = __float_as_uint(f);
    u += 0x7fff + ((u >> 16) & 1);          // RNE (finite values only)
    return (ushort_t)(u >> 16);
}
__device__ __forceinline__ float bf2f(ushort_t h) {
    return __uint_as_float((uint_t)h << 16);
}
__device__ __forceinline__ float bf2f_lo(uint_t v) { return __uint_as_float(v << 16); }
__device__ __forceinline__ float bf2f_hi(uint_t v) { return __uint_as_float(v & 0xffff0000u); }

// ---------------------------------------------------------------------------
// CSR build
// ---------------------------------------------------------------------------
__global__ void count_kernel(const int* __restrict__ ei, int* __restrict__ counts) {
    int i = blockIdx.x * blockDim.x + threadIdx.x;
    if (i >= ETOT) return;
    int dst = (i < N_EDGES) ? ei[N_EDGES + i] : (i - N_EDGES);
    atomicAdd(&counts[dst], 1);
}

__global__ __launch_bounds__(256) void block_sum_kernel(const int* __restrict__ counts,
                                                        int* __restrict__ blockSums, int n) {
    int b = blockIdx.x, t = threadIdx.x;
    int base = b * 1024 + t * 4;
    int s = 0;
    if (base + 3 < n) {
        int4 v = *reinterpret_cast<const int4*>(counts + base);
        s = v.x + v.y + v.z + v.w;
    } else {
        for (int i = 0; i < 4; i++) if (base + i < n) s += counts[base + i];
    }
    #pragma unroll
    for (int off = 32; off > 0; off >>= 1) s += __shfl_down(s, off);
    __shared__ int wsum[4];
    int lane = t & 63, wv = t >> 6;
    if (lane == 0) wsum[wv] = s;
    __syncthreads();
    if (t == 0) blockSums[b] = wsum[0] + wsum[1] + wsum[2] + wsum[3];
}

__global__ __launch_bounds__(256) void scan_sums_kernel(const int* __restrict__ blockSums,
                                                        int* __restrict__ blockBase, int nb) {
    __shared__ int sh[256];
    int t = threadIdx.x;
    int v = (t < nb) ? blockSums[t] : 0;
    sh[t] = v;
    __syncthreads();
    for (int off = 1; off < 256; off <<= 1) {
        int u = (t >= off) ? sh[t - off] : 0;
        __syncthreads();
        sh[t] += u;
        __syncthreads();
    }
    if (t < nb) blockBase[t] = sh[t] - v;
}

__global__ __launch_bounds__(256) void scan_final_kernel(const int* __restrict__ counts,
                                                         const int* __restrict__ blockBase,
                                                         int* __restrict__ offsets,
                                                         int* __restrict__ cursor, int n) {
    int b = blockIdx.x, t = threadIdx.x;
    int base = b * 1024 + t * 4;
    int c[4] = {0, 0, 0, 0};
    if (base + 3 < n) {
        int4 v = *reinterpret_cast<const int4*>(counts + base);
        c[0] = v.x; c[1] = v.y; c[2] = v.z; c[3] = v.w;
    } else {
        for (int i = 0; i < 4; i++) if (base + i < n) c[i] = counts[base + i];
    }
    int tsum = c[0] + c[1] + c[2] + c[3];
    int x = tsum;
    int lane = t & 63, wv = t >> 6;
    #pragma unroll
    for (int off = 1; off < 64; off <<= 1) {
        int u = __shfl_up(x, off);
        if (lane >= off) x += u;
    }
    __shared__ int wsum[4];
    if (lane == 63) wsum[wv] = x;
    __syncthreads();
    int wbase = 0;
    for (int w = 0; w < wv; w++) wbase += wsum[w];
    int run = blockBase[b] + wbase + (x - tsum);
    for (int i = 0; i < 4; i++) {
        if (base + i < n) { offsets[base + i] = run; cursor[base + i] = run; run += c[i]; }
    }
    if (b == 0 && t == 0) offsets[n] = ETOT;
}

__global__ void scatter_kernel(const int* __restrict__ ei, int* __restrict__ cursor,
                               int* __restrict__ csr_src) {
    int i = blockIdx.x * blockDim.x + threadIdx.x;
    if (i >= ETOT) return;
    int src, dst;
    if (i < N_EDGES) { src = ei[i]; dst = ei[N_EDGES + i]; }
    else             { src = dst = i - N_EDGES; }
    int pos = atomicAdd(&cursor[dst], 1);
    csr_src[pos] = src;
}

// ---------------------------------------------------------------------------
// MFMA GEMM: H[n][j] = sum_k X[n][k] * W[k][j], K=128, bf16 in/out, fp32 acc.
// Wave: 32 rows x OUT cols. W^T staged in LDS (bf16) with XOR swizzle so the
// B-frag ds_read_b128 is bank-conflict-free.
// ---------------------------------------------------------------------------
template <int OUT, bool IN_BF16>
__global__ __launch_bounds__(256) void gemm_mfma(const void* __restrict__ Xv,
                                                 const float* __restrict__ W,
                                                 ushort_t* __restrict__ Hout, int nrows) {
    constexpr int NB = OUT / 16;            // 8 or 4 col-tiles
    __shared__ ushort_t Wt[OUT * 128];      // swizzled [col][k]
    const int t = threadIdx.x;

    // ---- stage W^T (bf16, swizzled) ----
    {
        constexpr int GROUPS = 256 / OUT;   // 2 or 4
        constexpr int KPG    = 128 / GROUPS;
        int col = t & (OUT - 1);
        int kb0 = (t / OUT) * KPG;
        for (int c = 0; c < KPG / 8; c++) {
            int kb = kb0 + c * 8;
            short8 v;
            #pragma unroll
            for (int j = 0; j < 8; j++) v[j] = (short)f2bf(W[(kb + j) * OUT + col]);
            int off = col * 256 + (((kb >> 3) << 4) ^ ((col & 15) << 4));
            *reinterpret_cast<short8*>(reinterpret_cast<char*>(Wt) + off) = v;
        }
    }
    __syncthreads();

    const int wv = t >> 6, lane = t & 63;
    const int rowBase = (blockIdx.x * 4 + wv) * 32;
    if (rowBase >= nrows) return;
    const int r0 = lane & 15, g = lane >> 4;

    f32x4 acc[2][NB];
    #pragma unroll
    for (int rt = 0; rt < 2; rt++)
        #pragma unroll
        for (int nb = 0; nb < NB; nb++) acc[rt][nb] = {0.f, 0.f, 0.f, 0.f};

    #pragma unroll
    for (int step = 0; step < 4; step++) {
        short8 a0, a1;
        if (IN_BF16) {
            const ushort_t* X = (const ushort_t*)Xv;
            a0 = *reinterpret_cast<const short8*>(X + (size_t)(rowBase + r0) * 128 + step * 32 + g * 8);
            a1 = *reinterpret_cast<const short8*>(X + (size_t)(rowBase + 16 + r0) * 128 + step * 32 + g * 8);
        } else {
            const float* X = (const float*)Xv;
            const float* p0 = X + (size_t)(rowBase + r0) * 128 + step * 32 + g * 8;
            const float* p1 = X + (size_t)(rowBase + 16 + r0) * 128 + step * 32 + g * 8;
            #pragma unroll
            for (int j = 0; j < 8; j++) { a0[j] = (short)f2bf(p0[j]); a1[j] = (short)f2bf(p1[j]); }
        }
        const int chunkoff = (step << 6) + (g << 4);
        #pragma unroll
        for (int nb = 0; nb < NB; nb++) {
            int col = nb * 16 + r0;
            int off = col * 256 + (chunkoff ^ (r0 << 4));
            short8 b = *reinterpret_cast<const short8*>(reinterpret_cast<const char*>(Wt) + off);
            acc[0][nb] = __builtin_amdgcn_mfma_f32_16x16x32_bf16(a0, b, acc[0][nb], 0, 0, 0);
            acc[1][nb] = __builtin_amdgcn_mfma_f32_16x16x32_bf16(a1, b, acc[1][nb], 0, 0, 0);
        }
    }

    // epilogue: D col = lane&15, row = (lane>>4)*4 + reg   [m89-verified]
    #pragma unroll
    for (int rt = 0; rt < 2; rt++) {
        #pragma unroll
        for (int nb = 0; nb < NB; nb++) {
            #pragma unroll
            for (int rr = 0; rr < 4; rr++) {
                int row = rowBase + rt * 16 + g * 4 + rr;
                Hout[(size_t)row * OUT + nb * 16 + r0] = f2bf(acc[rt][nb][rr]);
            }
        }
    }
}

// ---------------------------------------------------------------------------
// Attention logits (bf16 features)
// ---------------------------------------------------------------------------
template <int H, int CP>
__global__ __launch_bounds__(256) void al_kernel(const ushort_t* __restrict__ Hf,
                                                 const float* __restrict__ a_s,
                                                 const float* __restrict__ a_d,
                                                 float* __restrict__ alS,
                                                 float* __restrict__ alD, int n) {
    constexpr int CT  = H * CP;
    constexpr int GPB = 256 / CP;
    int gid = blockIdx.x * GPB + threadIdx.x / CP;
    int c   = threadIdx.x % CP;
    if (gid >= n * H) return;
    int node = gid / H, h = gid % H;
    float v  = bf2f(Hf[(size_t)node * CT + h * CP + c]);
    float vs = v * a_s[h * CP + c];
    float vd = v * a_d[h * CP + c];
    #pragma unroll
    for (int off = CP / 2; off > 0; off >>= 1) {
        vs += __shfl_down(vs, off, CP);
        vd += __shfl_down(vd, off, CP);
    }
    if (c == 0) { alS[gid] = vs; alD[gid] = vd; }
}

// ---------------------------------------------------------------------------
// Softmax: wave per node, lanes over edges; butterfly (m,d) merge.
// ---------------------------------------------------------------------------
template <int H>
__global__ __launch_bounds__(256) void softmax_kernel(const float* __restrict__ alS,
                                                      const float* __restrict__ alD,
                                                      const int* __restrict__ offs,
                                                      const int* __restrict__ csr,
                                                      float* __restrict__ wgt,
                                                      float* __restrict__ rden, int n) {
    int wave = (blockIdx.x * blockDim.x + threadIdx.x) >> 6;
    int lane = threadIdx.x & 63;
    if (wave >= n) return;
    const int node = wave;
    const int s0 = offs[node], s1 = offs[node + 1];

    float ald[H], m[H], d[H];
    #pragma unroll
    for (int h = 0; h < H; h++) {
        ald[h] = alD[node * H + h];
        m[h] = -1e30f;
        d[h] = 0.0f;
    }

    for (int i = s0 + lane; i < s1; i += 64) {
        int s = csr[i];
        #pragma unroll
        for (int h = 0; h < H; h++) {
            float e = alS[s * H + h] + ald[h];
            e = (e > 0.0f) ? e : NEG_SLOPE * e;
            float nm = fmaxf(m[h], e);
            d[h] = d[h] * __expf(m[h] - nm) + __expf(e - nm);
            m[h] = nm;
        }
    }
    #pragma unroll
    for (int off = 32; off > 0; off >>= 1) {
        #pragma unroll
        for (int h = 0; h < H; h++) {
            float mo = __shfl_xor(m[h], off);
            float dd = __shfl_xor(d[h], off);
            float nm = fmaxf(m[h], mo);
            d[h] = d[h] * __expf(m[h] - nm) + dd * __expf(mo - nm);
            m[h] = nm;
        }
    }
    for (int i = s0 + lane; i < s1; i += 64) {
        int s = csr[i];
        #pragma unroll
        for (int h = 0; h < H; h++) {
            float e = alS[s * H + h] + ald[h];
            e = (e > 0.0f) ? e : NEG_SLOPE * e;
            wgt[i * H + h] = __expf(e - m[h]);
        }
    }
    if (lane == 0) {
        #pragma unroll
        for (int h = 0; h < H; h++)
            rden[node * H + h] = 1.0f / (d[h] + 1e-16f);
    }
}

// ---------------------------------------------------------------------------
// Aggregation, CT=128 (4 heads): lane owns channel pair (2*lane, 2*lane+1);
// one coalesced uint gather per edge per lane.
// ---------------------------------------------------------------------------
template <bool DO_ELU>
__global__ __launch_bounds__(256) void agg_128(const ushort_t* __restrict__ Hf,
                                               const float* __restrict__ wgt,
                                               const float* __restrict__ rden,
                                               const float* __restrict__ bias,
                                               const int* __restrict__ offs,
                                               const int* __restrict__ csr,
                                               ushort_t* __restrict__ out, int n) {
    int wave = (blockIdx.x * blockDim.x + threadIdx.x) >> 6;
    int lane = threadIdx.x & 63;
    if (wave >= n) return;
    const int node = wave;
    const int hh = lane >> 4;               // head of (2*lane)/32
    float acc0 = 0.f, acc1 = 0.f;

    const int s0 = offs[node], s1 = offs[node + 1];
    int i = s0;
    for (; i + 1 < s1; i += 2) {
        int sa = csr[i], sb = csr[i + 1];
        float wa = wgt[i * 4 + hh];
        float wb = wgt[(i + 1) * 4 + hh];
        uint_t va = *reinterpret_cast<const uint_t*>(Hf + (size_t)sa * 128 + lane * 2);
        uint_t vb = *reinterpret_cast<const uint_t*>(Hf + (size_t)sb * 128 + lane * 2);
        acc0 += wa * bf2f_lo(va); acc1 += wa * bf2f_hi(va);
        acc0 += wb * bf2f_lo(vb); acc1 += wb * bf2f_hi(vb);
    }
    if (i < s1) {
        int sa = csr[i];
        float wa = wgt[i * 4 + hh];
        uint_t va = *reinterpret_cast<const uint_t*>(Hf + (size_t)sa * 128 + lane * 2);
        acc0 += wa * bf2f_lo(va); acc1 += wa * bf2f_hi(va);
    }

    float rd = rden[node * 4 + hh];
    float o0 = acc0 * rd + bias[2 * lane];
    float o1 = acc1 * rd + bias[2 * lane + 1];
    if (DO_ELU) {
        o0 = (o0 > 0.0f) ? o0 : expm1f(o0);
        o1 = (o1 > 0.0f) ? o1 : expm1f(o1);
    }
    uint_t packed = (uint_t)f2bf(o0) | ((uint_t)f2bf(o1) << 16);
    *reinterpret_cast<uint_t*>(out + (size_t)node * 128 + lane * 2) = packed;
}

// Aggregation, CT=64 single head, fp32 output (final layer)
__global__ __launch_bounds__(256) void agg_64(const ushort_t* __restrict__ Hf,
                                              const float* __restrict__ wgt,
                                              const float* __restrict__ rden,
                                              const float* __restrict__ bias,
                                              const int* __restrict__ offs,
                                              const int* __restrict__ csr,
                                              float* __restrict__ out, int n) {
    int wave = (blockIdx.x * blockDim.x + threadIdx.x) >> 6;
    int lane = threadIdx.x & 63;
    if (wave >= n) return;
    const int node = wave;
    float acc = 0.f;
    const int s0 = offs[node], s1 = offs[node + 1];
    int i = s0;
    for (; i + 1 < s1; i += 2) {
        int sa = csr[i], sb = csr[i + 1];
        float wa = wgt[i], wb = wgt[i + 1];
        float ha = bf2f(Hf[(size_t)sa * 64 + lane]);
        float hb = bf2f(Hf[(size_t)sb * 64 + lane]);
        acc += wa * ha + wb * hb;
    }
    if (i < s1) acc += wgt[i] * bf2f(Hf[(size_t)csr[i] * 64 + lane]);
    out[(size_t)node * 64 + lane] = acc * rden[node] + bias[lane];
}

// ---------------------------------------------------------------------------
extern "C" void kernel_launch(void* const* d_in, const int* in_sizes, int n_in,
                              void* d_out, int out_size, void* d_ws, size_t ws_size,
                              hipStream_t stream) {
    const float* x   = (const float*)d_in[0];
    const int*   ei  = (const int*)d_in[1];
    const float* W0  = (const float*)d_in[2];
    const float* as0 = (const float*)d_in[3];
    const float* ad0 = (const float*)d_in[4];
    const float* b0  = (const float*)d_in[5];
    const float* W1  = (const float*)d_in[6];
    const float* as1 = (const float*)d_in[7];
    const float* ad1 = (const float*)d_in[8];
    const float* b1  = (const float*)d_in[9];
    const float* W2  = (const float*)d_in[10];
    const float* as2 = (const float*)d_in[11];
    const float* ad2 = (const float*)d_in[12];
    const float* b2  = (const float*)d_in[13];

    char* ws = (char*)d_ws;
    size_t off = 0;
    auto alloc = [&](size_t bytes) -> void* {
        void* p = ws + off;
        off += (bytes + 255) & ~size_t(255);
        return p;
    };
    ushort_t* B0   = (ushort_t*)alloc((size_t)N_NODES * 128 * sizeof(ushort_t));
    ushort_t* B1   = (ushort_t*)alloc((size_t)N_NODES * 128 * sizeof(ushort_t));
    float* alS     = (float*)alloc((size_t)N_NODES * 4 * sizeof(float));
    float* alD     = (float*)alloc((size_t)N_NODES * 4 * sizeof(float));
    float* wgt     = (float*)alloc((size_t)ETOT * 4 * sizeof(float));
    float* rden    = (float*)alloc((size_t)N_NODES * 4 * sizeof(float));
    int*   counts  = (int*)alloc((size_t)N_NODES * sizeof(int));
    int*   offs    = (int*)alloc((size_t)(N_NODES + 1) * sizeof(int));
    int*   cursor  = (int*)alloc((size_t)N_NODES * sizeof(int));
    int*   csr     = (int*)alloc((size_t)ETOT * sizeof(int));
    int*   bsums   = (int*)alloc(256 * sizeof(int));
    int*   bbase   = (int*)alloc(256 * sizeof(int));

    const int NB = (N_NODES + 1023) / 1024;

    // ---- CSR build ----
    hipMemsetAsync(counts, 0, (size_t)N_NODES * sizeof(int), stream);
    count_kernel<<<(ETOT + 255) / 256, 256, 0, stream>>>(ei, counts);
    block_sum_kernel<<<NB, 256, 0, stream>>>(counts, bsums, N_NODES);
    scan_sums_kernel<<<1, 256, 0, stream>>>(bsums, bbase, NB);
    scan_final_kernel<<<NB, 256, 0, stream>>>(counts, bbase, offs, cursor, N_NODES);
    scatter_kernel<<<(ETOT + 255) / 256, 256, 0, stream>>>(ei, cursor, csr);

    const int GEMM_GRID = (N_NODES / 32 + 3) / 4;       // 782 (32 rows/wave, 4 waves/block)
    const int NODE_WAVE_GRID = (N_NODES + 3) / 4;

    // ---- layer 0: fp32 x -> bf16 h ----
    gemm_mfma<128, false><<<GEMM_GRID, 256, 0, stream>>>(x, W0, B0, N_NODES);
    al_kernel<4, 32><<<(N_NODES * 4 + 7) / 8, 256, 0, stream>>>(B0, as0, ad0, alS, alD, N_NODES);
    softmax_kernel<4><<<NODE_WAVE_GRID, 256, 0, stream>>>(alS, alD, offs, csr, wgt, rden, N_NODES);
    agg_128<true><<<NODE_WAVE_GRID, 256, 0, stream>>>(B0, wgt, rden, b0, offs, csr, B1, N_NODES);

    // ---- layer 1 ----
    gemm_mfma<128, true><<<GEMM_GRID, 256, 0, stream>>>(B1, W1, B0, N_NODES);
    al_kernel<4, 32><<<(N_NODES * 4 + 7) / 8, 256, 0, stream>>>(B0, as1, ad1, alS, alD, N_NODES);
    softmax_kernel<4><<<NODE_WAVE_GRID, 256, 0, stream>>>(alS, alD, offs, csr, wgt, rden, N_NODES);
    agg_128<true><<<NODE_WAVE_GRID, 256, 0, stream>>>(B0, wgt, rden, b1, offs, csr, B1, N_NODES);

    // ---- layer 2: OUT=64, single head, fp32 out ----
    gemm_mfma<64, true><<<GEMM_GRID, 256, 0, stream>>>(B1, W2, B0, N_NODES);
    al_kernel<1, 64><<<(N_NODES + 3) / 4, 256, 0, stream>>>(B0, as2, ad2, alS, alD, N_NODES);
    softmax_kernel<1><<<NODE_WAVE_GRID, 256, 0, stream>>>(alS, alD, offs, csr, wgt, rden, N_NODES);
    agg_64<<<NODE_WAVE_GRID, 256, 0, stream>>>(B0, wgt, rden, b2, offs, csr,
                                               (float*)d_out, N_NODES);
}

// Round 5
// 643.577 us; speedup vs baseline: 1.4503x; 1.1370x over previous
//
#include <hip/hip_runtime.h>
#include <hip/hip_bf16.h>
#include <math.h>

#define N_NODES 100000
#define N_EDGES 1000000
#define ETOT    (N_EDGES + N_NODES)

#define NBUCK 391          // ceil(N_NODES/256): 256 nodes per bucket
#define BCAP  3584         // bucket capacity (mean 2813, ~15 sigma margin)
#define EPB_A 4096         // edges per phase-A block

constexpr float NEG_SLOPE = 0.2f;

typedef short short8 __attribute__((ext_vector_type(8)));
typedef float f32x4  __attribute__((ext_vector_type(4)));
typedef unsigned short ushort_t;
typedef unsigned int uint_t;
typedef long long ll_t;

__device__ __forceinline__ ushort_t f2bf(float f) {
    uint_t u = __float_as_uint(f);
    u += 0x7fff + ((u >> 16) & 1);          // RNE (finite values only)
    return (ushort_t)(u >> 16);
}
__device__ __forceinline__ float bf2f(ushort_t h) {
    return __uint_as_float((uint_t)h << 16);
}
__device__ __forceinline__ float bf2f_lo(uint_t v) { return __uint_as_float(v << 16); }
__device__ __forceinline__ float bf2f_hi(uint_t v) { return __uint_as_float(v & 0xffff0000u); }

// ---------------------------------------------------------------------------
// CSR build, bucketed (all global writes line-local):
//   init  : bucket cursors = b*BCAP
//   A     : bucket (src,dst) pairs by dst>>8, LDS-reordered, run-coalesced out
//   B1    : per-bucket LDS histogram -> counts (coalesced)
//   scans : counts -> offs (exclusive)
//   B2    : per-bucket scatter csr[pos]; window exclusive to one block
// ---------------------------------------------------------------------------
__global__ void binit_kernel(int* __restrict__ bcur) {
    int b = blockIdx.x * blockDim.x + threadIdx.x;
    if (b < NBUCK) bcur[b] = b * BCAP;
}

__global__ __launch_bounds__(256) void bucketA_kernel(const int* __restrict__ ei,
                                                      int* __restrict__ bcur,
                                                      ll_t* __restrict__ pairs) {
    __shared__ ll_t spair[EPB_A];
    __shared__ int  sgpos[EPB_A];
    __shared__ int  hist[NBUCK];
    __shared__ int  hscan[NBUCK];
    __shared__ int  base[NBUCK];
    __shared__ int  cur2[NBUCK];
    __shared__ int  sc[512];

    const int t = threadIdx.x;
    const int e0 = blockIdx.x * EPB_A;
    const int nvalid = min(EPB_A, ETOT - e0);

    for (int b = t; b < NBUCK; b += 256) { hist[b] = 0; cur2[b] = 0; }
    __syncthreads();

    // pass 1: histogram
    for (int r = 0; r < EPB_A / 256; r++) {
        int i = e0 + r * 256 + t;
        if (i < ETOT) {
            int dst = (i < N_EDGES) ? ei[N_EDGES + i] : (i - N_EDGES);
            atomicAdd(&hist[dst >> 8], 1);
        }
    }
    __syncthreads();

    // LDS inclusive scan over 512-padded hist (256 threads x 2 elems)
    sc[t]       = (t < NBUCK) ? hist[t] : 0;
    sc[t + 256] = (t + 256 < NBUCK) ? hist[t + 256] : 0;
    __syncthreads();
    for (int off = 1; off < 512; off <<= 1) {
        int v0 = (t >= off) ? sc[t - off] : 0;
        int v1 = sc[t + 256 - off];
        __syncthreads();
        sc[t] += v0;
        sc[t + 256] += v1;
        __syncthreads();
    }
    // exclusive scan + reserve global runs
    for (int b = t; b < NBUCK; b += 256) {
        hscan[b] = sc[b] - hist[b];
        if (hist[b] > 0) base[b] = atomicAdd(&bcur[b], hist[b]);
    }
    __syncthreads();

    // pass 2: reorder into LDS slots with global positions
    for (int r = 0; r < EPB_A / 256; r++) {
        int i = e0 + r * 256 + t;
        if (i < ETOT) {
            int src, dst;
            if (i < N_EDGES) { src = ei[i]; dst = ei[N_EDGES + i]; }
            else             { src = dst = i - N_EDGES; }
            int b = dst >> 8;
            int lr = atomicAdd(&cur2[b], 1);
            int slot = hscan[b] + lr;
            spair[slot] = ((ll_t)dst << 32) | (uint_t)src;
            sgpos[slot] = base[b] + lr;
        }
    }
    __syncthreads();

    // pass 3: run-coalesced writes (consecutive slots in a bucket run ->
    // consecutive global addresses)
    for (int s = t; s < nvalid; s += 256)
        pairs[sgpos[s]] = spair[s];
}

__global__ __launch_bounds__(256) void bucketB1_kernel(const ll_t* __restrict__ pairs,
                                                       const int* __restrict__ bcur,
                                                       int* __restrict__ counts) {
    __shared__ int h[256];
    const int b = blockIdx.x, t = threadIdx.x;
    h[t] = 0;
    __syncthreads();
    const int cnt = bcur[b] - b * BCAP;
    for (int i = t; i < cnt; i += 256) {
        int dst = (int)(pairs[(size_t)b * BCAP + i] >> 32);
        atomicAdd(&h[dst & 255], 1);
    }
    __syncthreads();
    int node = b * 256 + t;
    if (node < N_NODES) counts[node] = h[t];
}

__global__ __launch_bounds__(256) void bucketB2_kernel(const ll_t* __restrict__ pairs,
                                                       const int* __restrict__ bcur,
                                                       const int* __restrict__ offs,
                                                       int* __restrict__ csr) {
    __shared__ int cur[256];
    const int b = blockIdx.x, t = threadIdx.x;
    int node = b * 256 + t;
    cur[t] = (node < N_NODES) ? offs[node] : 0;
    __syncthreads();
    const int cnt = bcur[b] - b * BCAP;
    for (int i = t; i < cnt; i += 256) {
        ll_t p = pairs[(size_t)b * BCAP + i];
        int src = (int)(p & 0xffffffff);
        int dst = (int)(p >> 32);
        int pos = atomicAdd(&cur[dst & 255], 1);
        csr[pos] = src;
    }
}

// ---------------------------------------------------------------------------
// counts -> offs scans
// ---------------------------------------------------------------------------
__global__ __launch_bounds__(256) void block_sum_kernel(const int* __restrict__ counts,
                                                        int* __restrict__ blockSums, int n) {
    int b = blockIdx.x, t = threadIdx.x;
    int base = b * 1024 + t * 4;
    int s = 0;
    if (base + 3 < n) {
        int4 v = *reinterpret_cast<const int4*>(counts + base);
        s = v.x + v.y + v.z + v.w;
    } else {
        for (int i = 0; i < 4; i++) if (base + i < n) s += counts[base + i];
    }
    #pragma unroll
    for (int off = 32; off > 0; off >>= 1) s += __shfl_down(s, off);
    __shared__ int wsum[4];
    int lane = t & 63, wv = t >> 6;
    if (lane == 0) wsum[wv] = s;
    __syncthreads();
    if (t == 0) blockSums[b] = wsum[0] + wsum[1] + wsum[2] + wsum[3];
}

__global__ __launch_bounds__(256) void scan_sums_kernel(const int* __restrict__ blockSums,
                                                        int* __restrict__ blockBase, int nb) {
    __shared__ int sh[256];
    int t = threadIdx.x;
    int v = (t < nb) ? blockSums[t] : 0;
    sh[t] = v;
    __syncthreads();
    for (int off = 1; off < 256; off <<= 1) {
        int u = (t >= off) ? sh[t - off] : 0;
        __syncthreads();
        sh[t] += u;
        __syncthreads();
    }
    if (t < nb) blockBase[t] = sh[t] - v;
}

__global__ __launch_bounds__(256) void scan_final_kernel(const int* __restrict__ counts,
                                                         const int* __restrict__ blockBase,
                                                         int* __restrict__ offsets, int n) {
    int b = blockIdx.x, t = threadIdx.x;
    int base = b * 1024 + t * 4;
    int c[4] = {0, 0, 0, 0};
    if (base + 3 < n) {
        int4 v = *reinterpret_cast<const int4*>(counts + base);
        c[0] = v.x; c[1] = v.y; c[2] = v.z; c[3] = v.w;
    } else {
        for (int i = 0; i < 4; i++) if (base + i < n) c[i] = counts[base + i];
    }
    int tsum = c[0] + c[1] + c[2] + c[3];
    int x = tsum;
    int lane = t & 63, wv = t >> 6;
    #pragma unroll
    for (int off = 1; off < 64; off <<= 1) {
        int u = __shfl_up(x, off);
        if (lane >= off) x += u;
    }
    __shared__ int wsum[4];
    if (lane == 63) wsum[wv] = x;
    __syncthreads();
    int wbase = 0;
    for (int w = 0; w < wv; w++) wbase += wsum[w];
    int run = blockBase[b] + wbase + (x - tsum);
    for (int i = 0; i < 4; i++) {
        if (base + i < n) { offsets[base + i] = run; run += c[i]; }
    }
    if (b == 0 && t == 0) offsets[n] = ETOT;
}

// ---------------------------------------------------------------------------
// MFMA GEMM: H[n][j] = sum_k X[n][k] * W[k][j], K=128, bf16 in/out, fp32 acc.
// ---------------------------------------------------------------------------
template <int OUT, bool IN_BF16>
__global__ __launch_bounds__(256) void gemm_mfma(const void* __restrict__ Xv,
                                                 const float* __restrict__ W,
                                                 ushort_t* __restrict__ Hout, int nrows) {
    constexpr int NB = OUT / 16;
    __shared__ ushort_t Wt[OUT * 128];
    const int t = threadIdx.x;

    {
        constexpr int GROUPS = 256 / OUT;
        constexpr int KPG    = 128 / GROUPS;
        int col = t & (OUT - 1);
        int kb0 = (t / OUT) * KPG;
        for (int c = 0; c < KPG / 8; c++) {
            int kb = kb0 + c * 8;
            short8 v;
            #pragma unroll
            for (int j = 0; j < 8; j++) v[j] = (short)f2bf(W[(kb + j) * OUT + col]);
            int off = col * 256 + (((kb >> 3) << 4) ^ ((col & 15) << 4));
            *reinterpret_cast<short8*>(reinterpret_cast<char*>(Wt) + off) = v;
        }
    }
    __syncthreads();

    const int wv = t >> 6, lane = t & 63;
    const int rowBase = (blockIdx.x * 4 + wv) * 32;
    if (rowBase >= nrows) return;
    const int r0 = lane & 15, g = lane >> 4;

    f32x4 acc[2][NB];
    #pragma unroll
    for (int rt = 0; rt < 2; rt++)
        #pragma unroll
        for (int nb = 0; nb < NB; nb++) acc[rt][nb] = {0.f, 0.f, 0.f, 0.f};

    #pragma unroll
    for (int step = 0; step < 4; step++) {
        short8 a0, a1;
        if (IN_BF16) {
            const ushort_t* X = (const ushort_t*)Xv;
            a0 = *reinterpret_cast<const short8*>(X + (size_t)(rowBase + r0) * 128 + step * 32 + g * 8);
            a1 = *reinterpret_cast<const short8*>(X + (size_t)(rowBase + 16 + r0) * 128 + step * 32 + g * 8);
        } else {
            const float* X = (const float*)Xv;
            const float* p0 = X + (size_t)(rowBase + r0) * 128 + step * 32 + g * 8;
            const float* p1 = X + (size_t)(rowBase + 16 + r0) * 128 + step * 32 + g * 8;
            #pragma unroll
            for (int j = 0; j < 8; j++) { a0[j] = (short)f2bf(p0[j]); a1[j] = (short)f2bf(p1[j]); }
        }
        const int chunkoff = (step << 6) + (g << 4);
        #pragma unroll
        for (int nb = 0; nb < NB; nb++) {
            int col = nb * 16 + r0;
            int off = col * 256 + (chunkoff ^ (r0 << 4));
            short8 b = *reinterpret_cast<const short8*>(reinterpret_cast<const char*>(Wt) + off);
            acc[0][nb] = __builtin_amdgcn_mfma_f32_16x16x32_bf16(a0, b, acc[0][nb], 0, 0, 0);
            acc[1][nb] = __builtin_amdgcn_mfma_f32_16x16x32_bf16(a1, b, acc[1][nb], 0, 0, 0);
        }
    }

    #pragma unroll
    for (int rt = 0; rt < 2; rt++) {
        #pragma unroll
        for (int nb = 0; nb < NB; nb++) {
            #pragma unroll
            for (int rr = 0; rr < 4; rr++) {
                int row = rowBase + rt * 16 + g * 4 + rr;
                Hout[(size_t)row * OUT + nb * 16 + r0] = f2bf(acc[rt][nb][rr]);
            }
        }
    }
}

// ---------------------------------------------------------------------------
// Attention logits (bf16 features)
// ---------------------------------------------------------------------------
template <int H, int CP>
__global__ __launch_bounds__(256) void al_kernel(const ushort_t* __restrict__ Hf,
                                                 const float* __restrict__ a_s,
                                                 const float* __restrict__ a_d,
                                                 float* __restrict__ alS,
                                                 float* __restrict__ alD, int n) {
    constexpr int CT  = H * CP;
    constexpr int GPB = 256 / CP;
    int gid = blockIdx.x * GPB + threadIdx.x / CP;
    int c   = threadIdx.x % CP;
    if (gid >= n * H) return;
    int node = gid / H, h = gid % H;
    float v  = bf2f(Hf[(size_t)node * CT + h * CP + c]);
    float vs = v * a_s[h * CP + c];
    float vd = v * a_d[h * CP + c];
    #pragma unroll
    for (int off = CP / 2; off > 0; off >>= 1) {
        vs += __shfl_down(vs, off, CP);
        vd += __shfl_down(vd, off, CP);
    }
    if (c == 0) { alS[gid] = vs; alD[gid] = vd; }
}

// ---------------------------------------------------------------------------
// Softmax: wave per node, lanes over edges; butterfly (m,d) merge.
// ---------------------------------------------------------------------------
template <int H>
__global__ __launch_bounds__(256) void softmax_kernel(const float* __restrict__ alS,
                                                      const float* __restrict__ alD,
                                                      const int* __restrict__ offs,
                                                      const int* __restrict__ csr,
                                                      float* __restrict__ wgt,
                                                      float* __restrict__ rden, int n) {
    int wave = (blockIdx.x * blockDim.x + threadIdx.x) >> 6;
    int lane = threadIdx.x & 63;
    if (wave >= n) return;
    const int node = wave;
    const int s0 = offs[node], s1 = offs[node + 1];

    float ald[H], m[H], d[H];
    #pragma unroll
    for (int h = 0; h < H; h++) {
        ald[h] = alD[node * H + h];
        m[h] = -1e30f;
        d[h] = 0.0f;
    }

    for (int i = s0 + lane; i < s1; i += 64) {
        int s = csr[i];
        #pragma unroll
        for (int h = 0; h < H; h++) {
            float e = alS[s * H + h] + ald[h];
            e = (e > 0.0f) ? e : NEG_SLOPE * e;
            float nm = fmaxf(m[h], e);
            d[h] = d[h] * __expf(m[h] - nm) + __expf(e - nm);
            m[h] = nm;
        }
    }
    #pragma unroll
    for (int off = 32; off > 0; off >>= 1) {
        #pragma unroll
        for (int h = 0; h < H; h++) {
            float mo = __shfl_xor(m[h], off);
            float dd = __shfl_xor(d[h], off);
            float nm = fmaxf(m[h], mo);
            d[h] = d[h] * __expf(m[h] - nm) + dd * __expf(mo - nm);
            m[h] = nm;
        }
    }
    for (int i = s0 + lane; i < s1; i += 64) {
        int s = csr[i];
        #pragma unroll
        for (int h = 0; h < H; h++) {
            float e = alS[s * H + h] + ald[h];
            e = (e > 0.0f) ? e : NEG_SLOPE * e;
            wgt[i * H + h] = __expf(e - m[h]);
        }
    }
    if (lane == 0) {
        #pragma unroll
        for (int h = 0; h < H; h++)
            rden[node * H + h] = 1.0f / (d[h] + 1e-16f);
    }
}

// ---------------------------------------------------------------------------
// Aggregation, CT=128 (4 heads): lane owns channel pair; uint gather per edge.
// ---------------------------------------------------------------------------
template <bool DO_ELU>
__global__ __launch_bounds__(256) void agg_128(const ushort_t* __restrict__ Hf,
                                               const float* __restrict__ wgt,
                                               const float* __restrict__ rden,
                                               const float* __restrict__ bias,
                                               const int* __restrict__ offs,
                                               const int* __restrict__ csr,
                                               ushort_t* __restrict__ out, int n) {
    int wave = (blockIdx.x * blockDim.x + threadIdx.x) >> 6;
    int lane = threadIdx.x & 63;
    if (wave >= n) return;
    const int node = wave;
    const int hh = lane >> 4;
    float acc0 = 0.f, acc1 = 0.f;

    const int s0 = offs[node], s1 = offs[node + 1];
    int i = s0;
    for (; i + 1 < s1; i += 2) {
        int sa = csr[i], sb = csr[i + 1];
        float wa = wgt[i * 4 + hh];
        float wb = wgt[(i + 1) * 4 + hh];
        uint_t va = *reinterpret_cast<const uint_t*>(Hf + (size_t)sa * 128 + lane * 2);
        uint_t vb = *reinterpret_cast<const uint_t*>(Hf + (size_t)sb * 128 + lane * 2);
        acc0 += wa * bf2f_lo(va); acc1 += wa * bf2f_hi(va);
        acc0 += wb * bf2f_lo(vb); acc1 += wb * bf2f_hi(vb);
    }
    if (i < s1) {
        int sa = csr[i];
        float wa = wgt[i * 4 + hh];
        uint_t va = *reinterpret_cast<const uint_t*>(Hf + (size_t)sa * 128 + lane * 2);
        acc0 += wa * bf2f_lo(va); acc1 += wa * bf2f_hi(va);
    }

    float rd = rden[node * 4 + hh];
    float o0 = acc0 * rd + bias[2 * lane];
    float o1 = acc1 * rd + bias[2 * lane + 1];
    if (DO_ELU) {
        o0 = (o0 > 0.0f) ? o0 : expm1f(o0);
        o1 = (o1 > 0.0f) ? o1 : expm1f(o1);
    }
    uint_t packed = (uint_t)f2bf(o0) | ((uint_t)f2bf(o1) << 16);
    *reinterpret_cast<uint_t*>(out + (size_t)node * 128 + lane * 2) = packed;
}

__global__ __launch_bounds__(256) void agg_64(const ushort_t* __restrict__ Hf,
                                              const float* __restrict__ wgt,
                                              const float* __restrict__ rden,
                                              const float* __restrict__ bias,
                                              const int* __restrict__ offs,
                                              const int* __restrict__ csr,
                                              float* __restrict__ out, int n) {
    int wave = (blockIdx.x * blockDim.x + threadIdx.x) >> 6;
    int lane = threadIdx.x & 63;
    if (wave >= n) return;
    const int node = wave;
    float acc = 0.f;
    const int s0 = offs[node], s1 = offs[node + 1];
    int i = s0;
    for (; i + 1 < s1; i += 2) {
        int sa = csr[i], sb = csr[i + 1];
        float wa = wgt[i], wb = wgt[i + 1];
        float ha = bf2f(Hf[(size_t)sa * 64 + lane]);
        float hb = bf2f(Hf[(size_t)sb * 64 + lane]);
        acc += wa * ha + wb * hb;
    }
    if (i < s1) acc += wgt[i] * bf2f(Hf[(size_t)csr[i] * 64 + lane]);
    out[(size_t)node * 64 + lane] = acc * rden[node] + bias[lane];
}

// ---------------------------------------------------------------------------
extern "C" void kernel_launch(void* const* d_in, const int* in_sizes, int n_in,
                              void* d_out, int out_size, void* d_ws, size_t ws_size,
                              hipStream_t stream) {
    const float* x   = (const float*)d_in[0];
    const int*   ei  = (const int*)d_in[1];
    const float* W0  = (const float*)d_in[2];
    const float* as0 = (const float*)d_in[3];
    const float* ad0 = (const float*)d_in[4];
    const float* b0  = (const float*)d_in[5];
    const float* W1  = (const float*)d_in[6];
    const float* as1 = (const float*)d_in[7];
    const float* ad1 = (const float*)d_in[8];
    const float* b1  = (const float*)d_in[9];
    const float* W2  = (const float*)d_in[10];
    const float* as2 = (const float*)d_in[11];
    const float* ad2 = (const float*)d_in[12];
    const float* b2  = (const float*)d_in[13];

    char* ws = (char*)d_ws;
    size_t off = 0;
    auto alloc = [&](size_t bytes) -> void* {
        void* p = ws + off;
        off += (bytes + 255) & ~size_t(255);
        return p;
    };
    ushort_t* B0   = (ushort_t*)alloc((size_t)N_NODES * 128 * sizeof(ushort_t));
    ushort_t* B1   = (ushort_t*)alloc((size_t)N_NODES * 128 * sizeof(ushort_t));
    float* alS     = (float*)alloc((size_t)N_NODES * 4 * sizeof(float));
    float* alD     = (float*)alloc((size_t)N_NODES * 4 * sizeof(float));
    float* wgt     = (float*)alloc((size_t)ETOT * 4 * sizeof(float));
    float* rden    = (float*)alloc((size_t)N_NODES * 4 * sizeof(float));
    int*   counts  = (int*)alloc((size_t)N_NODES * sizeof(int));
    int*   offs    = (int*)alloc((size_t)(N_NODES + 1) * sizeof(int));
    int*   csr     = (int*)alloc((size_t)ETOT * sizeof(int));
    int*   bsums   = (int*)alloc(256 * sizeof(int));
    int*   bbase   = (int*)alloc(256 * sizeof(int));
    int*   bcur    = (int*)alloc((size_t)NBUCK * sizeof(int));
    ll_t*  pairs   = (ll_t*)alloc((size_t)NBUCK * BCAP * sizeof(ll_t));

    const int NB = (N_NODES + 1023) / 1024;

    // ---- CSR build (bucketed) ----
    binit_kernel<<<(NBUCK + 255) / 256, 256, 0, stream>>>(bcur);
    bucketA_kernel<<<(ETOT + EPB_A - 1) / EPB_A, 256, 0, stream>>>(ei, bcur, pairs);
    bucketB1_kernel<<<NBUCK, 256, 0, stream>>>(pairs, bcur, counts);
    block_sum_kernel<<<NB, 256, 0, stream>>>(counts, bsums, N_NODES);
    scan_sums_kernel<<<1, 256, 0, stream>>>(bsums, bbase, NB);
    scan_final_kernel<<<NB, 256, 0, stream>>>(counts, bbase, offs, N_NODES);
    bucketB2_kernel<<<NBUCK, 256, 0, stream>>>(pairs, bcur, offs, csr);

    const int GEMM_GRID = (N_NODES / 32 + 3) / 4;
    const int NODE_WAVE_GRID = (N_NODES + 3) / 4;

    // ---- layer 0: fp32 x -> bf16 h ----
    gemm_mfma<128, false><<<GEMM_GRID, 256, 0, stream>>>(x, W0, B0, N_NODES);
    al_kernel<4, 32><<<(N_NODES * 4 + 7) / 8, 256, 0, stream>>>(B0, as0, ad0, alS, alD, N_NODES);
    softmax_kernel<4><<<NODE_WAVE_GRID, 256, 0, stream>>>(alS, alD, offs, csr, wgt, rden, N_NODES);
    agg_128<true><<<NODE_WAVE_GRID, 256, 0, stream>>>(B0, wgt, rden, b0, offs, csr, B1, N_NODES);

    // ---- layer 1 ----
    gemm_mfma<128, true><<<GEMM_GRID, 256, 0, stream>>>(B1, W1, B0, N_NODES);
    al_kernel<4, 32><<<(N_NODES * 4 + 7) / 8, 256, 0, stream>>>(B0, as1, ad1, alS, alD, N_NODES);
    softmax_kernel<4><<<NODE_WAVE_GRID, 256, 0, stream>>>(alS, alD, offs, csr, wgt, rden, N_NODES);
    agg_128<true><<<NODE_WAVE_GRID, 256, 0, stream>>>(B0, wgt, rden, b1, offs, csr, B1, N_NODES);

    // ---- layer 2: OUT=64, single head, fp32 out ----
    gemm_mfma<64, true><<<GEMM_GRID, 256, 0, stream>>>(B1, W2, B0, N_NODES);
    al_kernel<1, 64><<<(N_NODES + 3) / 4, 256, 0, stream>>>(B0, as2, ad2, alS, alD, N_NODES);
    softmax_kernel<1><<<NODE_WAVE_GRID, 256, 0, stream>>>(alS, alD, offs, csr, wgt, rden, N_NODES);
    agg_64<<<NODE_WAVE_GRID, 256, 0, stream>>>(B0, wgt, rden, b2, offs, csr,
                                               (float*)d_out, N_NODES);
}

// Round 6
// 558.534 us; speedup vs baseline: 1.6711x; 1.1523x over previous
//
#include <hip/hip_runtime.h>
#include <hip/hip_bf16.h>
#include <math.h>

#define N_NODES 100000
#define N_EDGES 1000000
#define ETOT    (N_EDGES + N_NODES)

#define NBUCK 391          // ceil(N_NODES/256): 256 nodes per bucket
#define BCAP  3584         // bucket capacity (mean 2813, ~15 sigma margin)
#define EPB_A 4096         // edges per phase-A block

constexpr float NEG_SLOPE = 0.2f;

typedef short short8 __attribute__((ext_vector_type(8)));
typedef float f32x4  __attribute__((ext_vector_type(4)));
typedef unsigned short ushort_t;
typedef unsigned int uint_t;
typedef long long ll_t;

__device__ __forceinline__ ushort_t f2bf(float f) {
    uint_t u = __float_as_uint(f);
    u += 0x7fff + ((u >> 16) & 1);          // RNE (finite values only)
    return (ushort_t)(u >> 16);
}
__device__ __forceinline__ float bf2f(ushort_t h) {
    return __uint_as_float((uint_t)h << 16);
}
__device__ __forceinline__ float bf2f_lo(uint_t v) { return __uint_as_float(v << 16); }
__device__ __forceinline__ float bf2f_hi(uint_t v) { return __uint_as_float(v & 0xffff0000u); }

// ---------------------------------------------------------------------------
// CSR build, bucketed (all global writes line-local)
// ---------------------------------------------------------------------------
__global__ void binit_kernel(int* __restrict__ bcur) {
    int b = blockIdx.x * blockDim.x + threadIdx.x;
    if (b < NBUCK) bcur[b] = b * BCAP;
}

__global__ __launch_bounds__(256) void bucketA_kernel(const int* __restrict__ ei,
                                                      int* __restrict__ bcur,
                                                      ll_t* __restrict__ pairs) {
    __shared__ ll_t spair[EPB_A];
    __shared__ int  sgpos[EPB_A];
    __shared__ int  hist[NBUCK];
    __shared__ int  hscan[NBUCK];
    __shared__ int  base[NBUCK];
    __shared__ int  cur2[NBUCK];
    __shared__ int  sc[512];

    const int t = threadIdx.x;
    const int e0 = blockIdx.x * EPB_A;
    const int nvalid = min(EPB_A, ETOT - e0);

    for (int b = t; b < NBUCK; b += 256) { hist[b] = 0; cur2[b] = 0; }
    __syncthreads();

    for (int r = 0; r < EPB_A / 256; r++) {
        int i = e0 + r * 256 + t;
        if (i < ETOT) {
            int dst = (i < N_EDGES) ? ei[N_EDGES + i] : (i - N_EDGES);
            atomicAdd(&hist[dst >> 8], 1);
        }
    }
    __syncthreads();

    sc[t]       = (t < NBUCK) ? hist[t] : 0;
    sc[t + 256] = (t + 256 < NBUCK) ? hist[t + 256] : 0;
    __syncthreads();
    for (int off = 1; off < 512; off <<= 1) {
        int v0 = (t >= off) ? sc[t - off] : 0;
        int v1 = sc[t + 256 - off];
        __syncthreads();
        sc[t] += v0;
        sc[t + 256] += v1;
        __syncthreads();
    }
    for (int b = t; b < NBUCK; b += 256) {
        hscan[b] = sc[b] - hist[b];
        if (hist[b] > 0) base[b] = atomicAdd(&bcur[b], hist[b]);
    }
    __syncthreads();

    for (int r = 0; r < EPB_A / 256; r++) {
        int i = e0 + r * 256 + t;
        if (i < ETOT) {
            int src, dst;
            if (i < N_EDGES) { src = ei[i]; dst = ei[N_EDGES + i]; }
            else             { src = dst = i - N_EDGES; }
            int b = dst >> 8;
            int lr = atomicAdd(&cur2[b], 1);
            int slot = hscan[b] + lr;
            spair[slot] = ((ll_t)dst << 32) | (uint_t)src;
            sgpos[slot] = base[b] + lr;
        }
    }
    __syncthreads();

    for (int s = t; s < nvalid; s += 256)
        pairs[sgpos[s]] = spair[s];
}

__global__ __launch_bounds__(256) void bucketB1_kernel(const ll_t* __restrict__ pairs,
                                                       const int* __restrict__ bcur,
                                                       int* __restrict__ counts) {
    __shared__ int h[256];
    const int b = blockIdx.x, t = threadIdx.x;
    h[t] = 0;
    __syncthreads();
    const int cnt = bcur[b] - b * BCAP;
    for (int i = t; i < cnt; i += 256) {
        int dst = (int)(pairs[(size_t)b * BCAP + i] >> 32);
        atomicAdd(&h[dst & 255], 1);
    }
    __syncthreads();
    int node = b * 256 + t;
    if (node < N_NODES) counts[node] = h[t];
}

__global__ __launch_bounds__(256) void bucketB2_kernel(const ll_t* __restrict__ pairs,
                                                       const int* __restrict__ bcur,
                                                       const int* __restrict__ offs,
                                                       int* __restrict__ csr) {
    __shared__ int cur[256];
    const int b = blockIdx.x, t = threadIdx.x;
    int node = b * 256 + t;
    cur[t] = (node < N_NODES) ? offs[node] : 0;
    __syncthreads();
    const int cnt = bcur[b] - b * BCAP;
    for (int i = t; i < cnt; i += 256) {
        ll_t p = pairs[(size_t)b * BCAP + i];
        int src = (int)(p & 0xffffffff);
        int dst = (int)(p >> 32);
        int pos = atomicAdd(&cur[dst & 255], 1);
        csr[pos] = src;
    }
}

// ---------------------------------------------------------------------------
// counts -> offs scans
// ---------------------------------------------------------------------------
__global__ __launch_bounds__(256) void block_sum_kernel(const int* __restrict__ counts,
                                                        int* __restrict__ blockSums, int n) {
    int b = blockIdx.x, t = threadIdx.x;
    int base = b * 1024 + t * 4;
    int s = 0;
    if (base + 3 < n) {
        int4 v = *reinterpret_cast<const int4*>(counts + base);
        s = v.x + v.y + v.z + v.w;
    } else {
        for (int i = 0; i < 4; i++) if (base + i < n) s += counts[base + i];
    }
    #pragma unroll
    for (int off = 32; off > 0; off >>= 1) s += __shfl_down(s, off);
    __shared__ int wsum[4];
    int lane = t & 63, wv = t >> 6;
    if (lane == 0) wsum[wv] = s;
    __syncthreads();
    if (t == 0) blockSums[b] = wsum[0] + wsum[1] + wsum[2] + wsum[3];
}

__global__ __launch_bounds__(256) void scan_sums_kernel(const int* __restrict__ blockSums,
                                                        int* __restrict__ blockBase, int nb) {
    __shared__ int sh[256];
    int t = threadIdx.x;
    int v = (t < nb) ? blockSums[t] : 0;
    sh[t] = v;
    __syncthreads();
    for (int off = 1; off < 256; off <<= 1) {
        int u = (t >= off) ? sh[t - off] : 0;
        __syncthreads();
        sh[t] += u;
        __syncthreads();
    }
    if (t < nb) blockBase[t] = sh[t] - v;
}

__global__ __launch_bounds__(256) void scan_final_kernel(const int* __restrict__ counts,
                                                         const int* __restrict__ blockBase,
                                                         int* __restrict__ offsets, int n) {
    int b = blockIdx.x, t = threadIdx.x;
    int base = b * 1024 + t * 4;
    int c[4] = {0, 0, 0, 0};
    if (base + 3 < n) {
        int4 v = *reinterpret_cast<const int4*>(counts + base);
        c[0] = v.x; c[1] = v.y; c[2] = v.z; c[3] = v.w;
    } else {
        for (int i = 0; i < 4; i++) if (base + i < n) c[i] = counts[base + i];
    }
    int tsum = c[0] + c[1] + c[2] + c[3];
    int x = tsum;
    int lane = t & 63, wv = t >> 6;
    #pragma unroll
    for (int off = 1; off < 64; off <<= 1) {
        int u = __shfl_up(x, off);
        if (lane >= off) x += u;
    }
    __shared__ int wsum[4];
    if (lane == 63) wsum[wv] = x;
    __syncthreads();
    int wbase = 0;
    for (int w = 0; w < wv; w++) wbase += wsum[w];
    int run = blockBase[b] + wbase + (x - tsum);
    for (int i = 0; i < 4; i++) {
        if (base + i < n) { offsets[base + i] = run; run += c[i]; }
    }
    if (b == 0 && t == 0) offsets[n] = ETOT;
}

// ---------------------------------------------------------------------------
// MFMA GEMM with FUSED attention-logit epilogue.
// H[n][j] = sum_k X[n][k]*W[k][j]; alS/alD[n,h] = dot(h[n,head h], a_{s,d}[h]).
// Wave: 32 rows x OUT cols. D-frag layout: col = lane&15, row = (lane>>4)*4+reg.
// ---------------------------------------------------------------------------
template <int OUT, int H, bool IN_BF16>
__global__ __launch_bounds__(256) void gemm_mfma(const void* __restrict__ Xv,
                                                 const float* __restrict__ W,
                                                 const float* __restrict__ a_s,
                                                 const float* __restrict__ a_d,
                                                 ushort_t* __restrict__ Hout,
                                                 float* __restrict__ alS,
                                                 float* __restrict__ alD, int nrows) {
    constexpr int NB  = OUT / 16;     // col tiles: 8 or 4
    constexpr int CPH = OUT / H;      // channels per head: 32 or 64
    constexpr int TPH = NB / H;       // col tiles per head: 2 or 4
    __shared__ ushort_t Wt[OUT * 128];
    const int t = threadIdx.x;

    {
        constexpr int GROUPS = 256 / OUT;
        constexpr int KPG    = 128 / GROUPS;
        int col = t & (OUT - 1);
        int kb0 = (t / OUT) * KPG;
        for (int c = 0; c < KPG / 8; c++) {
            int kb = kb0 + c * 8;
            short8 v;
            #pragma unroll
            for (int j = 0; j < 8; j++) v[j] = (short)f2bf(W[(kb + j) * OUT + col]);
            int off = col * 256 + (((kb >> 3) << 4) ^ ((col & 15) << 4));
            *reinterpret_cast<short8*>(reinterpret_cast<char*>(Wt) + off) = v;
        }
    }
    __syncthreads();

    const int wv = t >> 6, lane = t & 63;
    const int rowBase = (blockIdx.x * 4 + wv) * 32;
    if (rowBase >= nrows) return;
    const int r0 = lane & 15, g = lane >> 4;

    f32x4 acc[2][NB];
    #pragma unroll
    for (int rt = 0; rt < 2; rt++)
        #pragma unroll
        for (int nb = 0; nb < NB; nb++) acc[rt][nb] = {0.f, 0.f, 0.f, 0.f};

    #pragma unroll
    for (int step = 0; step < 4; step++) {
        short8 a0, a1;
        if (IN_BF16) {
            const ushort_t* X = (const ushort_t*)Xv;
            a0 = *reinterpret_cast<const short8*>(X + (size_t)(rowBase + r0) * 128 + step * 32 + g * 8);
            a1 = *reinterpret_cast<const short8*>(X + (size_t)(rowBase + 16 + r0) * 128 + step * 32 + g * 8);
        } else {
            const float* X = (const float*)Xv;
            const float* p0 = X + (size_t)(rowBase + r0) * 128 + step * 32 + g * 8;
            const float* p1 = X + (size_t)(rowBase + 16 + r0) * 128 + step * 32 + g * 8;
            #pragma unroll
            for (int j = 0; j < 8; j++) { a0[j] = (short)f2bf(p0[j]); a1[j] = (short)f2bf(p1[j]); }
        }
        const int chunkoff = (step << 6) + (g << 4);
        #pragma unroll
        for (int nb = 0; nb < NB; nb++) {
            int col = nb * 16 + r0;
            int off = col * 256 + (chunkoff ^ (r0 << 4));
            short8 b = *reinterpret_cast<const short8*>(reinterpret_cast<const char*>(Wt) + off);
            acc[0][nb] = __builtin_amdgcn_mfma_f32_16x16x32_bf16(a0, b, acc[0][nb], 0, 0, 0);
            acc[1][nb] = __builtin_amdgcn_mfma_f32_16x16x32_bf16(a1, b, acc[1][nb], 0, 0, 0);
        }
    }

    // ---- store bf16 H ----
    #pragma unroll
    for (int rt = 0; rt < 2; rt++) {
        #pragma unroll
        for (int nb = 0; nb < NB; nb++) {
            #pragma unroll
            for (int rr = 0; rr < 4; rr++) {
                int row = rowBase + rt * 16 + g * 4 + rr;
                Hout[(size_t)row * OUT + nb * 16 + r0] = f2bf(acc[rt][nb][rr]);
            }
        }
    }

    // ---- fused attention logits (from fp32 acc) ----
    float asv[NB], adv[NB];
    #pragma unroll
    for (int nb = 0; nb < NB; nb++) {
        int col = nb * 16 + r0;
        int h = col / CPH, c = col % CPH;
        asv[nb] = a_s[h * CPH + c];
        adv[nb] = a_d[h * CPH + c];
    }
    #pragma unroll
    for (int rt = 0; rt < 2; rt++) {
        #pragma unroll
        for (int rr = 0; rr < 4; rr++) {
            int row = rowBase + rt * 16 + g * 4 + rr;
            #pragma unroll
            for (int h = 0; h < H; h++) {
                float vs = 0.f, vd = 0.f;
                #pragma unroll
                for (int tt = 0; tt < TPH; tt++) {
                    int nb = h * TPH + tt;
                    vs += acc[rt][nb][rr] * asv[nb];
                    vd += acc[rt][nb][rr] * adv[nb];
                }
                #pragma unroll
                for (int off = 8; off > 0; off >>= 1) {
                    vs += __shfl_xor(vs, off, 16);
                    vd += __shfl_xor(vd, off, 16);
                }
                if (r0 == 0) {
                    alS[row * H + h] = vs;
                    alD[row * H + h] = vd;
                }
            }
        }
    }
}

// ---------------------------------------------------------------------------
// Stats: per-(node,head) softmax max (mx) + reciprocal denom (rden).
// One wave per node, lanes over edges; butterfly (m,d) merge.
// ---------------------------------------------------------------------------
template <int H>
__global__ __launch_bounds__(256) void stats_kernel(const float* __restrict__ alS,
                                                    const float* __restrict__ alD,
                                                    const int* __restrict__ offs,
                                                    const int* __restrict__ csr,
                                                    float* __restrict__ mx,
                                                    float* __restrict__ rden, int n) {
    int wave = (blockIdx.x * blockDim.x + threadIdx.x) >> 6;
    int lane = threadIdx.x & 63;
    if (wave >= n) return;
    const int node = wave;
    const int s0 = offs[node], s1 = offs[node + 1];

    float ald[H], m[H], d[H];
    #pragma unroll
    for (int h = 0; h < H; h++) {
        ald[h] = alD[node * H + h];
        m[h] = -1e30f;
        d[h] = 0.0f;
    }

    for (int i = s0 + lane; i < s1; i += 64) {
        int s = csr[i];
        if (H == 4) {
            float4 av = *reinterpret_cast<const float4*>(alS + s * 4);
            float ev[4] = {av.x, av.y, av.z, av.w};
            #pragma unroll
            for (int h = 0; h < 4; h++) {
                float e = ev[h] + ald[h];
                e = (e > 0.0f) ? e : NEG_SLOPE * e;
                float nm = fmaxf(m[h], e);
                d[h] = d[h] * __expf(m[h] - nm) + __expf(e - nm);
                m[h] = nm;
            }
        } else {
            float e = alS[s] + ald[0];
            e = (e > 0.0f) ? e : NEG_SLOPE * e;
            float nm = fmaxf(m[0], e);
            d[0] = d[0] * __expf(m[0] - nm) + __expf(e - nm);
            m[0] = nm;
        }
    }
    #pragma unroll
    for (int off = 32; off > 0; off >>= 1) {
        #pragma unroll
        for (int h = 0; h < H; h++) {
            float mo = __shfl_xor(m[h], off);
            float dd = __shfl_xor(d[h], off);
            float nm = fmaxf(m[h], mo);
            d[h] = d[h] * __expf(m[h] - nm) + dd * __expf(mo - nm);
            m[h] = nm;
        }
    }
    if (lane == 0) {
        #pragma unroll
        for (int h = 0; h < H; h++) {
            mx[node * H + h] = m[h];
            rden[node * H + h] = 1.0f / (d[h] + 1e-16f);
        }
    }
}

// ---------------------------------------------------------------------------
// Aggregation CT=128 (4 heads), fused weight recompute:
// w = exp(leaky(alS[s,h]+alD[n,h]) - mx[n,h]); acc += w * Hf[s,ch]. 4-edge unroll.
// ---------------------------------------------------------------------------
template <bool DO_ELU>
__global__ __launch_bounds__(256) void agg_128(const ushort_t* __restrict__ Hf,
                                               const float* __restrict__ alS,
                                               const float* __restrict__ alD,
                                               const float* __restrict__ mx,
                                               const float* __restrict__ rden,
                                               const float* __restrict__ bias,
                                               const int* __restrict__ offs,
                                               const int* __restrict__ csr,
                                               ushort_t* __restrict__ out, int n) {
    int wave = (blockIdx.x * blockDim.x + threadIdx.x) >> 6;
    int lane = threadIdx.x & 63;
    if (wave >= n) return;
    const int node = wave;
    const int hh = lane >> 4;
    const float aldn = alD[node * 4 + hh];
    const float mn   = mx[node * 4 + hh];
    float acc0 = 0.f, acc1 = 0.f;

    const int s0 = offs[node], s1 = offs[node + 1];
    int i = s0;
    for (; i + 3 < s1; i += 4) {
        int sa = csr[i], sb = csr[i + 1], sc_ = csr[i + 2], sd = csr[i + 3];
        float ea = alS[sa * 4 + hh], eb = alS[sb * 4 + hh];
        float ec = alS[sc_ * 4 + hh], ed = alS[sd * 4 + hh];
        uint_t va = *reinterpret_cast<const uint_t*>(Hf + (size_t)sa * 128 + lane * 2);
        uint_t vb = *reinterpret_cast<const uint_t*>(Hf + (size_t)sb * 128 + lane * 2);
        uint_t vc = *reinterpret_cast<const uint_t*>(Hf + (size_t)sc_ * 128 + lane * 2);
        uint_t vd = *reinterpret_cast<const uint_t*>(Hf + (size_t)sd * 128 + lane * 2);
        ea += aldn; ea = (ea > 0.f) ? ea : NEG_SLOPE * ea; float wa = __expf(ea - mn);
        eb += aldn; eb = (eb > 0.f) ? eb : NEG_SLOPE * eb; float wb = __expf(eb - mn);
        ec += aldn; ec = (ec > 0.f) ? ec : NEG_SLOPE * ec; float wc = __expf(ec - mn);
        ed += aldn; ed = (ed > 0.f) ? ed : NEG_SLOPE * ed; float wd = __expf(ed - mn);
        acc0 += wa * bf2f_lo(va); acc1 += wa * bf2f_hi(va);
        acc0 += wb * bf2f_lo(vb); acc1 += wb * bf2f_hi(vb);
        acc0 += wc * bf2f_lo(vc); acc1 += wc * bf2f_hi(vc);
        acc0 += wd * bf2f_lo(vd); acc1 += wd * bf2f_hi(vd);
    }
    for (; i < s1; i++) {
        int sa = csr[i];
        float ea = alS[sa * 4 + hh];
        uint_t va = *reinterpret_cast<const uint_t*>(Hf + (size_t)sa * 128 + lane * 2);
        ea += aldn; ea = (ea > 0.f) ? ea : NEG_SLOPE * ea; float wa = __expf(ea - mn);
        acc0 += wa * bf2f_lo(va); acc1 += wa * bf2f_hi(va);
    }

    float rd = rden[node * 4 + hh];
    float o0 = acc0 * rd + bias[2 * lane];
    float o1 = acc1 * rd + bias[2 * lane + 1];
    if (DO_ELU) {
        o0 = (o0 > 0.0f) ? o0 : expm1f(o0);
        o1 = (o1 > 0.0f) ? o1 : expm1f(o1);
    }
    uint_t packed = (uint_t)f2bf(o0) | ((uint_t)f2bf(o1) << 16);
    *reinterpret_cast<uint_t*>(out + (size_t)node * 128 + lane * 2) = packed;
}

// Aggregation CT=64 single head, fused weights, fp32 output (final layer)
__global__ __launch_bounds__(256) void agg_64(const ushort_t* __restrict__ Hf,
                                              const float* __restrict__ alS,
                                              const float* __restrict__ alD,
                                              const float* __restrict__ mx,
                                              const float* __restrict__ rden,
                                              const float* __restrict__ bias,
                                              const int* __restrict__ offs,
                                              const int* __restrict__ csr,
                                              float* __restrict__ out, int n) {
    int wave = (blockIdx.x * blockDim.x + threadIdx.x) >> 6;
    int lane = threadIdx.x & 63;
    if (wave >= n) return;
    const int node = wave;
    const float aldn = alD[node];
    const float mn   = mx[node];
    float acc = 0.f;
    const int s0 = offs[node], s1 = offs[node + 1];
    int i = s0;
    for (; i + 1 < s1; i += 2) {
        int sa = csr[i], sb = csr[i + 1];
        float ea = alS[sa], eb = alS[sb];
        float ha = bf2f(Hf[(size_t)sa * 64 + lane]);
        float hb = bf2f(Hf[(size_t)sb * 64 + lane]);
        ea += aldn; ea = (ea > 0.f) ? ea : NEG_SLOPE * ea; float wa = __expf(ea - mn);
        eb += aldn; eb = (eb > 0.f) ? eb : NEG_SLOPE * eb; float wb = __expf(eb - mn);
        acc += wa * ha + wb * hb;
    }
    if (i < s1) {
        int sa = csr[i];
        float ea = alS[sa];
        ea += aldn; ea = (ea > 0.f) ? ea : NEG_SLOPE * ea;
        acc += __expf(ea - mn) * bf2f(Hf[(size_t)sa * 64 + lane]);
    }
    out[(size_t)node * 64 + lane] = acc * rden[node] + bias[lane];
}

// ---------------------------------------------------------------------------
extern "C" void kernel_launch(void* const* d_in, const int* in_sizes, int n_in,
                              void* d_out, int out_size, void* d_ws, size_t ws_size,
                              hipStream_t stream) {
    const float* x   = (const float*)d_in[0];
    const int*   ei  = (const int*)d_in[1];
    const float* W0  = (const float*)d_in[2];
    const float* as0 = (const float*)d_in[3];
    const float* ad0 = (const float*)d_in[4];
    const float* b0  = (const float*)d_in[5];
    const float* W1  = (const float*)d_in[6];
    const float* as1 = (const float*)d_in[7];
    const float* ad1 = (const float*)d_in[8];
    const float* b1  = (const float*)d_in[9];
    const float* W2  = (const float*)d_in[10];
    const float* as2 = (const float*)d_in[11];
    const float* ad2 = (const float*)d_in[12];
    const float* b2  = (const float*)d_in[13];

    char* ws = (char*)d_ws;
    size_t off = 0;
    auto alloc = [&](size_t bytes) -> void* {
        void* p = ws + off;
        off += (bytes + 255) & ~size_t(255);
        return p;
    };
    ushort_t* B0   = (ushort_t*)alloc((size_t)N_NODES * 128 * sizeof(ushort_t));
    ushort_t* B1   = (ushort_t*)alloc((size_t)N_NODES * 128 * sizeof(ushort_t));
    float* alS     = (float*)alloc((size_t)N_NODES * 4 * sizeof(float));
    float* alD     = (float*)alloc((size_t)N_NODES * 4 * sizeof(float));
    float* mx      = (float*)alloc((size_t)N_NODES * 4 * sizeof(float));
    float* rden    = (float*)alloc((size_t)N_NODES * 4 * sizeof(float));
    int*   counts  = (int*)alloc((size_t)N_NODES * sizeof(int));
    int*   offs    = (int*)alloc((size_t)(N_NODES + 1) * sizeof(int));
    int*   csr     = (int*)alloc((size_t)ETOT * sizeof(int));
    int*   bsums   = (int*)alloc(256 * sizeof(int));
    int*   bbase   = (int*)alloc(256 * sizeof(int));
    int*   bcur    = (int*)alloc((size_t)NBUCK * sizeof(int));
    ll_t*  pairs   = (ll_t*)alloc((size_t)NBUCK * BCAP * sizeof(ll_t));

    const int NB = (N_NODES + 1023) / 1024;

    // ---- CSR build (bucketed) ----
    binit_kernel<<<(NBUCK + 255) / 256, 256, 0, stream>>>(bcur);
    bucketA_kernel<<<(ETOT + EPB_A - 1) / EPB_A, 256, 0, stream>>>(ei, bcur, pairs);
    bucketB1_kernel<<<NBUCK, 256, 0, stream>>>(pairs, bcur, counts);
    block_sum_kernel<<<NB, 256, 0, stream>>>(counts, bsums, N_NODES);
    scan_sums_kernel<<<1, 256, 0, stream>>>(bsums, bbase, NB);
    scan_final_kernel<<<NB, 256, 0, stream>>>(counts, bbase, offs, N_NODES);
    bucketB2_kernel<<<NBUCK, 256, 0, stream>>>(pairs, bcur, offs, csr);

    const int GEMM_GRID = (N_NODES / 32 + 3) / 4;
    const int NODE_WAVE_GRID = (N_NODES + 3) / 4;

    // ---- layer 0: fp32 x -> bf16 h (al fused into GEMM epilogue) ----
    gemm_mfma<128, 4, false><<<GEMM_GRID, 256, 0, stream>>>(x, W0, as0, ad0, B0, alS, alD, N_NODES);
    stats_kernel<4><<<NODE_WAVE_GRID, 256, 0, stream>>>(alS, alD, offs, csr, mx, rden, N_NODES);
    agg_128<true><<<NODE_WAVE_GRID, 256, 0, stream>>>(B0, alS, alD, mx, rden, b0, offs, csr, B1, N_NODES);

    // ---- layer 1 ----
    gemm_mfma<128, 4, true><<<GEMM_GRID, 256, 0, stream>>>(B1, W1, as1, ad1, B0, alS, alD, N_NODES);
    stats_kernel<4><<<NODE_WAVE_GRID, 256, 0, stream>>>(alS, alD, offs, csr, mx, rden, N_NODES);
    agg_128<true><<<NODE_WAVE_GRID, 256, 0, stream>>>(B0, alS, alD, mx, rden, b1, offs, csr, B1, N_NODES);

    // ---- layer 2: OUT=64, single head, fp32 out ----
    gemm_mfma<64, 1, true><<<GEMM_GRID, 256, 0, stream>>>(B1, W2, as2, ad2, B0, alS, alD, N_NODES);
    stats_kernel<1><<<NODE_WAVE_GRID, 256, 0, stream>>>(alS, alD, offs, csr, mx, rden, N_NODES);
    agg_64<<<NODE_WAVE_GRID, 256, 0, stream>>>(B0, alS, alD, mx, rden, b2, offs, csr,
                                               (float*)d_out, N_NODES);
}

// Round 7
// 482.557 us; speedup vs baseline: 1.9342x; 1.1574x over previous
//
#include <hip/hip_runtime.h>
#include <hip/hip_bf16.h>
#include <math.h>

#define N_NODES 100000
#define N_EDGES 1000000
#define ETOT    (N_EDGES + N_NODES)

#define NBUCK 391          // ceil(N_NODES/256): 256 nodes per bucket
#define BCAP  3584         // bucket capacity (mean 2813, ~15 sigma margin)
#define EPB_A 4096         // edges per phase-A block

constexpr float NEG_SLOPE = 0.2f;

typedef short short8 __attribute__((ext_vector_type(8)));
typedef float f32x4  __attribute__((ext_vector_type(4)));
typedef unsigned short ushort_t;
typedef unsigned int uint_t;
typedef long long ll_t;

__device__ __forceinline__ ushort_t f2bf(float f) {
    uint_t u = __float_as_uint(f);
    u += 0x7fff + ((u >> 16) & 1);          // RNE (finite values only)
    return (ushort_t)(u >> 16);
}
__device__ __forceinline__ float bf2f(ushort_t h) {
    return __uint_as_float((uint_t)h << 16);
}
__device__ __forceinline__ float bf2f_lo(uint_t v) { return __uint_as_float(v << 16); }
__device__ __forceinline__ float bf2f_hi(uint_t v) { return __uint_as_float(v & 0xffff0000u); }

// ---------------------------------------------------------------------------
// CSR build, bucketed (all global writes line-local)
// ---------------------------------------------------------------------------
__global__ void binit_kernel(int* __restrict__ bcur) {
    int b = blockIdx.x * blockDim.x + threadIdx.x;
    if (b < NBUCK) bcur[b] = b * BCAP;
}

__global__ __launch_bounds__(256) void bucketA_kernel(const int* __restrict__ ei,
                                                      int* __restrict__ bcur,
                                                      ll_t* __restrict__ pairs) {
    __shared__ ll_t spair[EPB_A];
    __shared__ int  sgpos[EPB_A];
    __shared__ int  hist[NBUCK];
    __shared__ int  hscan[NBUCK];
    __shared__ int  base[NBUCK];
    __shared__ int  cur2[NBUCK];
    __shared__ int  sc[512];

    const int t = threadIdx.x;
    const int e0 = blockIdx.x * EPB_A;
    const int nvalid = min(EPB_A, ETOT - e0);

    for (int b = t; b < NBUCK; b += 256) { hist[b] = 0; cur2[b] = 0; }
    __syncthreads();

    for (int r = 0; r < EPB_A / 256; r++) {
        int i = e0 + r * 256 + t;
        if (i < ETOT) {
            int dst = (i < N_EDGES) ? ei[N_EDGES + i] : (i - N_EDGES);
            atomicAdd(&hist[dst >> 8], 1);
        }
    }
    __syncthreads();

    sc[t]       = (t < NBUCK) ? hist[t] : 0;
    sc[t + 256] = (t + 256 < NBUCK) ? hist[t + 256] : 0;
    __syncthreads();
    for (int off = 1; off < 512; off <<= 1) {
        int v0 = (t >= off) ? sc[t - off] : 0;
        int v1 = sc[t + 256 - off];
        __syncthreads();
        sc[t] += v0;
        sc[t + 256] += v1;
        __syncthreads();
    }
    for (int b = t; b < NBUCK; b += 256) {
        hscan[b] = sc[b] - hist[b];
        if (hist[b] > 0) base[b] = atomicAdd(&bcur[b], hist[b]);
    }
    __syncthreads();

    for (int r = 0; r < EPB_A / 256; r++) {
        int i = e0 + r * 256 + t;
        if (i < ETOT) {
            int src, dst;
            if (i < N_EDGES) { src = ei[i]; dst = ei[N_EDGES + i]; }
            else             { src = dst = i - N_EDGES; }
            int b = dst >> 8;
            int lr = atomicAdd(&cur2[b], 1);
            int slot = hscan[b] + lr;
            spair[slot] = ((ll_t)dst << 32) | (uint_t)src;
            sgpos[slot] = base[b] + lr;
        }
    }
    __syncthreads();

    for (int s = t; s < nvalid; s += 256)
        pairs[sgpos[s]] = spair[s];
}

__global__ __launch_bounds__(256) void bucketB1_kernel(const ll_t* __restrict__ pairs,
                                                       const int* __restrict__ bcur,
                                                       int* __restrict__ counts) {
    __shared__ int h[256];
    const int b = blockIdx.x, t = threadIdx.x;
    h[t] = 0;
    __syncthreads();
    const int cnt = bcur[b] - b * BCAP;
    for (int i = t; i < cnt; i += 256) {
        int dst = (int)(pairs[(size_t)b * BCAP + i] >> 32);
        atomicAdd(&h[dst & 255], 1);
    }
    __syncthreads();
    int node = b * 256 + t;
    if (node < N_NODES) counts[node] = h[t];
}

__global__ __launch_bounds__(256) void bucketB2_kernel(const ll_t* __restrict__ pairs,
                                                       const int* __restrict__ bcur,
                                                       const int* __restrict__ offs,
                                                       int* __restrict__ csr) {
    __shared__ int cur[256];
    const int b = blockIdx.x, t = threadIdx.x;
    int node = b * 256 + t;
    cur[t] = (node < N_NODES) ? offs[node] : 0;
    __syncthreads();
    const int cnt = bcur[b] - b * BCAP;
    for (int i = t; i < cnt; i += 256) {
        ll_t p = pairs[(size_t)b * BCAP + i];
        int src = (int)(p & 0xffffffff);
        int dst = (int)(p >> 32);
        int pos = atomicAdd(&cur[dst & 255], 1);
        csr[pos] = src;
    }
}

// ---------------------------------------------------------------------------
// counts -> offs scans
// ---------------------------------------------------------------------------
__global__ __launch_bounds__(256) void block_sum_kernel(const int* __restrict__ counts,
                                                        int* __restrict__ blockSums, int n) {
    int b = blockIdx.x, t = threadIdx.x;
    int base = b * 1024 + t * 4;
    int s = 0;
    if (base + 3 < n) {
        int4 v = *reinterpret_cast<const int4*>(counts + base);
        s = v.x + v.y + v.z + v.w;
    } else {
        for (int i = 0; i < 4; i++) if (base + i < n) s += counts[base + i];
    }
    #pragma unroll
    for (int off = 32; off > 0; off >>= 1) s += __shfl_down(s, off);
    __shared__ int wsum[4];
    int lane = t & 63, wv = t >> 6;
    if (lane == 0) wsum[wv] = s;
    __syncthreads();
    if (t == 0) blockSums[b] = wsum[0] + wsum[1] + wsum[2] + wsum[3];
}

__global__ __launch_bounds__(256) void scan_sums_kernel(const int* __restrict__ blockSums,
                                                        int* __restrict__ blockBase, int nb) {
    __shared__ int sh[256];
    int t = threadIdx.x;
    int v = (t < nb) ? blockSums[t] : 0;
    sh[t] = v;
    __syncthreads();
    for (int off = 1; off < 256; off <<= 1) {
        int u = (t >= off) ? sh[t - off] : 0;
        __syncthreads();
        sh[t] += u;
        __syncthreads();
    }
    if (t < nb) blockBase[t] = sh[t] - v;
}

__global__ __launch_bounds__(256) void scan_final_kernel(const int* __restrict__ counts,
                                                         const int* __restrict__ blockBase,
                                                         int* __restrict__ offsets, int n) {
    int b = blockIdx.x, t = threadIdx.x;
    int base = b * 1024 + t * 4;
    int c[4] = {0, 0, 0, 0};
    if (base + 3 < n) {
        int4 v = *reinterpret_cast<const int4*>(counts + base);
        c[0] = v.x; c[1] = v.y; c[2] = v.z; c[3] = v.w;
    } else {
        for (int i = 0; i < 4; i++) if (base + i < n) c[i] = counts[base + i];
    }
    int tsum = c[0] + c[1] + c[2] + c[3];
    int x = tsum;
    int lane = t & 63, wv = t >> 6;
    #pragma unroll
    for (int off = 1; off < 64; off <<= 1) {
        int u = __shfl_up(x, off);
        if (lane >= off) x += u;
    }
    __shared__ int wsum[4];
    if (lane == 63) wsum[wv] = x;
    __syncthreads();
    int wbase = 0;
    for (int w = 0; w < wv; w++) wbase += wsum[w];
    int run = blockBase[b] + wbase + (x - tsum);
    for (int i = 0; i < 4; i++) {
        if (base + i < n) { offsets[base + i] = run; run += c[i]; }
    }
    if (b == 0 && t == 0) offsets[n] = ETOT;
}

// ---------------------------------------------------------------------------
// MFMA GEMM with FUSED attention-logit epilogue.
// ---------------------------------------------------------------------------
template <int OUT, int H, bool IN_BF16>
__global__ __launch_bounds__(256) void gemm_mfma(const void* __restrict__ Xv,
                                                 const float* __restrict__ W,
                                                 const float* __restrict__ a_s,
                                                 const float* __restrict__ a_d,
                                                 ushort_t* __restrict__ Hout,
                                                 float* __restrict__ alS,
                                                 float* __restrict__ alD, int nrows) {
    constexpr int NB  = OUT / 16;
    constexpr int CPH = OUT / H;
    constexpr int TPH = NB / H;
    __shared__ ushort_t Wt[OUT * 128];
    const int t = threadIdx.x;

    {
        constexpr int GROUPS = 256 / OUT;
        constexpr int KPG    = 128 / GROUPS;
        int col = t & (OUT - 1);
        int kb0 = (t / OUT) * KPG;
        for (int c = 0; c < KPG / 8; c++) {
            int kb = kb0 + c * 8;
            short8 v;
            #pragma unroll
            for (int j = 0; j < 8; j++) v[j] = (short)f2bf(W[(kb + j) * OUT + col]);
            int off = col * 256 + (((kb >> 3) << 4) ^ ((col & 15) << 4));
            *reinterpret_cast<short8*>(reinterpret_cast<char*>(Wt) + off) = v;
        }
    }
    __syncthreads();

    const int wv = t >> 6, lane = t & 63;
    const int rowBase = (blockIdx.x * 4 + wv) * 32;
    if (rowBase >= nrows) return;
    const int r0 = lane & 15, g = lane >> 4;

    f32x4 acc[2][NB];
    #pragma unroll
    for (int rt = 0; rt < 2; rt++)
        #pragma unroll
        for (int nb = 0; nb < NB; nb++) acc[rt][nb] = {0.f, 0.f, 0.f, 0.f};

    #pragma unroll
    for (int step = 0; step < 4; step++) {
        short8 a0, a1;
        if (IN_BF16) {
            const ushort_t* X = (const ushort_t*)Xv;
            a0 = *reinterpret_cast<const short8*>(X + (size_t)(rowBase + r0) * 128 + step * 32 + g * 8);
            a1 = *reinterpret_cast<const short8*>(X + (size_t)(rowBase + 16 + r0) * 128 + step * 32 + g * 8);
        } else {
            const float* X = (const float*)Xv;
            const float* p0 = X + (size_t)(rowBase + r0) * 128 + step * 32 + g * 8;
            const float* p1 = X + (size_t)(rowBase + 16 + r0) * 128 + step * 32 + g * 8;
            #pragma unroll
            for (int j = 0; j < 8; j++) { a0[j] = (short)f2bf(p0[j]); a1[j] = (short)f2bf(p1[j]); }
        }
        const int chunkoff = (step << 6) + (g << 4);
        #pragma unroll
        for (int nb = 0; nb < NB; nb++) {
            int col = nb * 16 + r0;
            int off = col * 256 + (chunkoff ^ (r0 << 4));
            short8 b = *reinterpret_cast<const short8*>(reinterpret_cast<const char*>(Wt) + off);
            acc[0][nb] = __builtin_amdgcn_mfma_f32_16x16x32_bf16(a0, b, acc[0][nb], 0, 0, 0);
            acc[1][nb] = __builtin_amdgcn_mfma_f32_16x16x32_bf16(a1, b, acc[1][nb], 0, 0, 0);
        }
    }

    #pragma unroll
    for (int rt = 0; rt < 2; rt++) {
        #pragma unroll
        for (int nb = 0; nb < NB; nb++) {
            #pragma unroll
            for (int rr = 0; rr < 4; rr++) {
                int row = rowBase + rt * 16 + g * 4 + rr;
                Hout[(size_t)row * OUT + nb * 16 + r0] = f2bf(acc[rt][nb][rr]);
            }
        }
    }

    float asv[NB], adv[NB];
    #pragma unroll
    for (int nb = 0; nb < NB; nb++) {
        int col = nb * 16 + r0;
        int h = col / CPH, c = col % CPH;
        asv[nb] = a_s[h * CPH + c];
        adv[nb] = a_d[h * CPH + c];
    }
    #pragma unroll
    for (int rt = 0; rt < 2; rt++) {
        #pragma unroll
        for (int rr = 0; rr < 4; rr++) {
            int row = rowBase + rt * 16 + g * 4 + rr;
            #pragma unroll
            for (int h = 0; h < H; h++) {
                float vs = 0.f, vd = 0.f;
                #pragma unroll
                for (int tt = 0; tt < TPH; tt++) {
                    int nb = h * TPH + tt;
                    vs += acc[rt][nb][rr] * asv[nb];
                    vd += acc[rt][nb][rr] * adv[nb];
                }
                #pragma unroll
                for (int off = 8; off > 0; off >>= 1) {
                    vs += __shfl_xor(vs, off, 16);
                    vd += __shfl_xor(vd, off, 16);
                }
                if (r0 == 0) {
                    alS[row * H + h] = vs;
                    alD[row * H + h] = vd;
                }
            }
        }
    }
}

// ---------------------------------------------------------------------------
// Fused stats+aggregation, CT=128 (4 heads).
// Pass 1: lanes over edges, online (m,d) per head, full butterfly -> all
// lanes hold m,d. Pass 2: lane owns channel pair, recompute w inline.
// ---------------------------------------------------------------------------
template <bool DO_ELU>
__global__ __launch_bounds__(256) void agg128_fused(const ushort_t* __restrict__ Hf,
                                                    const float* __restrict__ alS,
                                                    const float* __restrict__ alD,
                                                    const float* __restrict__ bias,
                                                    const int* __restrict__ offs,
                                                    const int* __restrict__ csr,
                                                    ushort_t* __restrict__ out, int n) {
    int wave = (blockIdx.x * blockDim.x + threadIdx.x) >> 6;
    int lane = threadIdx.x & 63;
    if (wave >= n) return;
    const int node = wave;
    const int s0 = offs[node], s1 = offs[node + 1];

    float ald4[4];
    {
        float4 t4 = *reinterpret_cast<const float4*>(alD + node * 4);
        ald4[0] = t4.x; ald4[1] = t4.y; ald4[2] = t4.z; ald4[3] = t4.w;
    }

    // ---- pass 1: (m,d) per head ----
    float m[4], d[4];
    #pragma unroll
    for (int h = 0; h < 4; h++) { m[h] = -1e30f; d[h] = 0.0f; }
    for (int i = s0 + lane; i < s1; i += 64) {
        int s = csr[i];
        float4 av = *reinterpret_cast<const float4*>(alS + s * 4);
        float ev[4] = {av.x, av.y, av.z, av.w};
        #pragma unroll
        for (int h = 0; h < 4; h++) {
            float e = ev[h] + ald4[h];
            e = (e > 0.0f) ? e : NEG_SLOPE * e;
            float nm = fmaxf(m[h], e);
            d[h] = d[h] * __expf(m[h] - nm) + __expf(e - nm);
            m[h] = nm;
        }
    }
    #pragma unroll
    for (int off = 32; off > 0; off >>= 1) {
        #pragma unroll
        for (int h = 0; h < 4; h++) {
            float mo = __shfl_xor(m[h], off);
            float dd = __shfl_xor(d[h], off);
            float nm = fmaxf(m[h], mo);
            d[h] = d[h] * __expf(m[h] - nm) + dd * __expf(mo - nm);
            m[h] = nm;
        }
    }

    // ---- pass 2: aggregate (lane = channel pair) ----
    const int hh = lane >> 4;
    const float aldn = ald4[hh];
    const float mn   = m[hh];
    const float rd   = 1.0f / (d[hh] + 1e-16f);
    float acc0 = 0.f, acc1 = 0.f;

    int i = s0;
    for (; i + 3 < s1; i += 4) {
        int sa = csr[i], sb = csr[i + 1], sc_ = csr[i + 2], sd = csr[i + 3];
        float ea = alS[sa * 4 + hh], eb = alS[sb * 4 + hh];
        float ec = alS[sc_ * 4 + hh], ed = alS[sd * 4 + hh];
        uint_t va = *reinterpret_cast<const uint_t*>(Hf + (size_t)sa * 128 + lane * 2);
        uint_t vb = *reinterpret_cast<const uint_t*>(Hf + (size_t)sb * 128 + lane * 2);
        uint_t vc = *reinterpret_cast<const uint_t*>(Hf + (size_t)sc_ * 128 + lane * 2);
        uint_t vd = *reinterpret_cast<const uint_t*>(Hf + (size_t)sd * 128 + lane * 2);
        ea += aldn; ea = (ea > 0.f) ? ea : NEG_SLOPE * ea; float wa = __expf(ea - mn);
        eb += aldn; eb = (eb > 0.f) ? eb : NEG_SLOPE * eb; float wb = __expf(eb - mn);
        ec += aldn; ec = (ec > 0.f) ? ec : NEG_SLOPE * ec; float wc = __expf(ec - mn);
        ed += aldn; ed = (ed > 0.f) ? ed : NEG_SLOPE * ed; float wd = __expf(ed - mn);
        acc0 += wa * bf2f_lo(va); acc1 += wa * bf2f_hi(va);
        acc0 += wb * bf2f_lo(vb); acc1 += wb * bf2f_hi(vb);
        acc0 += wc * bf2f_lo(vc); acc1 += wc * bf2f_hi(vc);
        acc0 += wd * bf2f_lo(vd); acc1 += wd * bf2f_hi(vd);
    }
    for (; i < s1; i++) {
        int sa = csr[i];
        float ea = alS[sa * 4 + hh];
        uint_t va = *reinterpret_cast<const uint_t*>(Hf + (size_t)sa * 128 + lane * 2);
        ea += aldn; ea = (ea > 0.f) ? ea : NEG_SLOPE * ea; float wa = __expf(ea - mn);
        acc0 += wa * bf2f_lo(va); acc1 += wa * bf2f_hi(va);
    }

    float o0 = acc0 * rd + bias[2 * lane];
    float o1 = acc1 * rd + bias[2 * lane + 1];
    if (DO_ELU) {
        o0 = (o0 > 0.0f) ? o0 : expm1f(o0);
        o1 = (o1 > 0.0f) ? o1 : expm1f(o1);
    }
    uint_t packed = (uint_t)f2bf(o0) | ((uint_t)f2bf(o1) << 16);
    *reinterpret_cast<uint_t*>(out + (size_t)node * 128 + lane * 2) = packed;
}

// ---------------------------------------------------------------------------
// Fused stats+aggregation, CT=64 single head, fp32 output.
// Pass 2 uses HALF-WAVE per edge: 32 lanes x uint (2 ch) cover the 64-ch row;
// wave retires 2 edges/iter (4 with unroll). Halves combined via shfl_xor(32).
// ---------------------------------------------------------------------------
__global__ __launch_bounds__(256) void agg64_fused(const ushort_t* __restrict__ Hf,
                                                   const float* __restrict__ alS,
                                                   const float* __restrict__ alD,
                                                   const float* __restrict__ bias,
                                                   const int* __restrict__ offs,
                                                   const int* __restrict__ csr,
                                                   float* __restrict__ out, int n) {
    int wave = (blockIdx.x * blockDim.x + threadIdx.x) >> 6;
    int lane = threadIdx.x & 63;
    if (wave >= n) return;
    const int node = wave;
    const int s0 = offs[node], s1 = offs[node + 1];
    const float aldn = alD[node];

    // ---- pass 1: (m,d) ----
    float m = -1e30f, d = 0.0f;
    for (int i = s0 + lane; i < s1; i += 64) {
        float e = alS[csr[i]] + aldn;
        e = (e > 0.0f) ? e : NEG_SLOPE * e;
        float nm = fmaxf(m, e);
        d = d * __expf(m - nm) + __expf(e - nm);
        m = nm;
    }
    #pragma unroll
    for (int off = 32; off > 0; off >>= 1) {
        float mo = __shfl_xor(m, off);
        float dd = __shfl_xor(d, off);
        float nm = fmaxf(m, mo);
        d = d * __expf(m - nm) + dd * __expf(mo - nm);
        m = nm;
    }
    const float mn = m;
    const float rd = 1.0f / (d + 1e-16f);

    // ---- pass 2: half-wave per edge ----
    const int eh = lane >> 5;        // which edge of the pair
    const int c2 = lane & 31;        // uint index (channels 2*c2, 2*c2+1)
    float acc0 = 0.f, acc1 = 0.f;

    int i = s0;
    for (; i + 3 < s1; i += 4) {
        int sa = csr[i + eh];
        int sb = csr[i + 2 + eh];
        float ea = alS[sa], eb = alS[sb];
        uint_t va = *reinterpret_cast<const uint_t*>(Hf + (size_t)sa * 64 + c2 * 2);
        uint_t vb = *reinterpret_cast<const uint_t*>(Hf + (size_t)sb * 64 + c2 * 2);
        ea += aldn; ea = (ea > 0.f) ? ea : NEG_SLOPE * ea; float wa = __expf(ea - mn);
        eb += aldn; eb = (eb > 0.f) ? eb : NEG_SLOPE * eb; float wb = __expf(eb - mn);
        acc0 += wa * bf2f_lo(va); acc1 += wa * bf2f_hi(va);
        acc0 += wb * bf2f_lo(vb); acc1 += wb * bf2f_hi(vb);
    }
    for (; i < s1; i += 2) {
        int idx = i + eh;
        if (idx < s1) {
            int sa = csr[idx];
            float ea = alS[sa];
            uint_t va = *reinterpret_cast<const uint_t*>(Hf + (size_t)sa * 64 + c2 * 2);
            ea += aldn; ea = (ea > 0.f) ? ea : NEG_SLOPE * ea; float wa = __expf(ea - mn);
            acc0 += wa * bf2f_lo(va); acc1 += wa * bf2f_hi(va);
        }
    }

    acc0 += __shfl_xor(acc0, 32);
    acc1 += __shfl_xor(acc1, 32);
    if (lane < 32) {
        float2 o;
        o.x = acc0 * rd + bias[2 * c2];
        o.y = acc1 * rd + bias[2 * c2 + 1];
        *reinterpret_cast<float2*>(out + (size_t)node * 64 + c2 * 2) = o;
    }
}

// ---------------------------------------------------------------------------
extern "C" void kernel_launch(void* const* d_in, const int* in_sizes, int n_in,
                              void* d_out, int out_size, void* d_ws, size_t ws_size,
                              hipStream_t stream) {
    const float* x   = (const float*)d_in[0];
    const int*   ei  = (const int*)d_in[1];
    const float* W0  = (const float*)d_in[2];
    const float* as0 = (const float*)d_in[3];
    const float* ad0 = (const float*)d_in[4];
    const float* b0  = (const float*)d_in[5];
    const float* W1  = (const float*)d_in[6];
    const float* as1 = (const float*)d_in[7];
    const float* ad1 = (const float*)d_in[8];
    const float* b1  = (const float*)d_in[9];
    const float* W2  = (const float*)d_in[10];
    const float* as2 = (const float*)d_in[11];
    const float* ad2 = (const float*)d_in[12];
    const float* b2  = (const float*)d_in[13];

    char* ws = (char*)d_ws;
    size_t off = 0;
    auto alloc = [&](size_t bytes) -> void* {
        void* p = ws + off;
        off += (bytes + 255) & ~size_t(255);
        return p;
    };
    ushort_t* B0   = (ushort_t*)alloc((size_t)N_NODES * 128 * sizeof(ushort_t));
    ushort_t* B1   = (ushort_t*)alloc((size_t)N_NODES * 128 * sizeof(ushort_t));
    float* alS     = (float*)alloc((size_t)N_NODES * 4 * sizeof(float));
    float* alD     = (float*)alloc((size_t)N_NODES * 4 * sizeof(float));
    int*   counts  = (int*)alloc((size_t)N_NODES * sizeof(int));
    int*   offs    = (int*)alloc((size_t)(N_NODES + 1) * sizeof(int));
    int*   csr     = (int*)alloc((size_t)ETOT * sizeof(int));
    int*   bsums   = (int*)alloc(256 * sizeof(int));
    int*   bbase   = (int*)alloc(256 * sizeof(int));
    int*   bcur    = (int*)alloc((size_t)NBUCK * sizeof(int));
    ll_t*  pairs   = (ll_t*)alloc((size_t)NBUCK * BCAP * sizeof(ll_t));

    const int NB = (N_NODES + 1023) / 1024;

    // ---- CSR build (bucketed) ----
    binit_kernel<<<(NBUCK + 255) / 256, 256, 0, stream>>>(bcur);
    bucketA_kernel<<<(ETOT + EPB_A - 1) / EPB_A, 256, 0, stream>>>(ei, bcur, pairs);
    bucketB1_kernel<<<NBUCK, 256, 0, stream>>>(pairs, bcur, counts);
    block_sum_kernel<<<NB, 256, 0, stream>>>(counts, bsums, N_NODES);
    scan_sums_kernel<<<1, 256, 0, stream>>>(bsums, bbase, NB);
    scan_final_kernel<<<NB, 256, 0, stream>>>(counts, bbase, offs, N_NODES);
    bucketB2_kernel<<<NBUCK, 256, 0, stream>>>(pairs, bcur, offs, csr);

    const int GEMM_GRID = (N_NODES / 32 + 3) / 4;
    const int NODE_WAVE_GRID = (N_NODES + 3) / 4;

    // ---- layer 0: fp32 x -> bf16 h (al fused into GEMM epilogue) ----
    gemm_mfma<128, 4, false><<<GEMM_GRID, 256, 0, stream>>>(x, W0, as0, ad0, B0, alS, alD, N_NODES);
    agg128_fused<true><<<NODE_WAVE_GRID, 256, 0, stream>>>(B0, alS, alD, b0, offs, csr, B1, N_NODES);

    // ---- layer 1 ----
    gemm_mfma<128, 4, true><<<GEMM_GRID, 256, 0, stream>>>(B1, W1, as1, ad1, B0, alS, alD, N_NODES);
    agg128_fused<true><<<NODE_WAVE_GRID, 256, 0, stream>>>(B0, alS, alD, b1, offs, csr, B1, N_NODES);

    // ---- layer 2: OUT=64, single head, fp32 out ----
    gemm_mfma<64, 1, true><<<GEMM_GRID, 256, 0, stream>>>(B1, W2, as2, ad2, B0, alS, alD, N_NODES);
    agg64_fused<<<NODE_WAVE_GRID, 256, 0, stream>>>(B0, alS, alD, b2, offs, csr,
                                                    (float*)d_out, N_NODES);
}

// Round 8
// 398.706 us; speedup vs baseline: 2.3410x; 1.2103x over previous
//
#include <hip/hip_runtime.h>
#include <hip/hip_bf16.h>
#include <math.h>

#define N_NODES 100000
#define N_EDGES 1000000
#define ETOT    (N_EDGES + N_NODES)

#define NBUCK 391          // ceil(N_NODES/256): 256 nodes per bucket
#define BCAP  3584         // bucket capacity (mean 2813, ~15 sigma margin)
#define EPB_A 4096         // edges per phase-A block

constexpr float NEG_SLOPE = 0.2f;

typedef short short8 __attribute__((ext_vector_type(8)));
typedef float f32x4  __attribute__((ext_vector_type(4)));
typedef unsigned short ushort_t;
typedef unsigned int uint_t;
typedef long long ll_t;

__device__ __forceinline__ ushort_t f2bf(float f) {
    uint_t u = __float_as_uint(f);
    u += 0x7fff + ((u >> 16) & 1);          // RNE (finite values only)
    return (ushort_t)(u >> 16);
}
__device__ __forceinline__ float bf2f(ushort_t h) {
    return __uint_as_float((uint_t)h << 16);
}
__device__ __forceinline__ float bf2f_lo(uint_t v) { return __uint_as_float(v << 16); }
__device__ __forceinline__ float bf2f_hi(uint_t v) { return __uint_as_float(v & 0xffff0000u); }

// ---------------------------------------------------------------------------
// CSR build, bucketed (all global writes line-local)
// ---------------------------------------------------------------------------
__global__ void binit_kernel(int* __restrict__ bcur) {
    int b = blockIdx.x * blockDim.x + threadIdx.x;
    if (b < NBUCK) bcur[b] = b * BCAP;
}

__global__ __launch_bounds__(256) void bucketA_kernel(const int* __restrict__ ei,
                                                      int* __restrict__ bcur,
                                                      ll_t* __restrict__ pairs) {
    __shared__ ll_t spair[EPB_A];
    __shared__ int  sgpos[EPB_A];
    __shared__ int  hist[NBUCK];
    __shared__ int  hscan[NBUCK];
    __shared__ int  base[NBUCK];
    __shared__ int  cur2[NBUCK];
    __shared__ int  sc[512];

    const int t = threadIdx.x;
    const int e0 = blockIdx.x * EPB_A;
    const int nvalid = min(EPB_A, ETOT - e0);

    for (int b = t; b < NBUCK; b += 256) { hist[b] = 0; cur2[b] = 0; }
    __syncthreads();

    for (int r = 0; r < EPB_A / 256; r++) {
        int i = e0 + r * 256 + t;
        if (i < ETOT) {
            int dst = (i < N_EDGES) ? ei[N_EDGES + i] : (i - N_EDGES);
            atomicAdd(&hist[dst >> 8], 1);
        }
    }
    __syncthreads();

    sc[t]       = (t < NBUCK) ? hist[t] : 0;
    sc[t + 256] = (t + 256 < NBUCK) ? hist[t + 256] : 0;
    __syncthreads();
    for (int off = 1; off < 512; off <<= 1) {
        int v0 = (t >= off) ? sc[t - off] : 0;
        int v1 = sc[t + 256 - off];
        __syncthreads();
        sc[t] += v0;
        sc[t + 256] += v1;
        __syncthreads();
    }
    for (int b = t; b < NBUCK; b += 256) {
        hscan[b] = sc[b] - hist[b];
        if (hist[b] > 0) base[b] = atomicAdd(&bcur[b], hist[b]);
    }
    __syncthreads();

    for (int r = 0; r < EPB_A / 256; r++) {
        int i = e0 + r * 256 + t;
        if (i < ETOT) {
            int src, dst;
            if (i < N_EDGES) { src = ei[i]; dst = ei[N_EDGES + i]; }
            else             { src = dst = i - N_EDGES; }
            int b = dst >> 8;
            int lr = atomicAdd(&cur2[b], 1);
            int slot = hscan[b] + lr;
            spair[slot] = ((ll_t)dst << 32) | (uint_t)src;
            sgpos[slot] = base[b] + lr;
        }
    }
    __syncthreads();

    for (int s = t; s < nvalid; s += 256)
        pairs[sgpos[s]] = spair[s];
}

__global__ __launch_bounds__(256) void bucketB1_kernel(const ll_t* __restrict__ pairs,
                                                       const int* __restrict__ bcur,
                                                       int* __restrict__ counts) {
    __shared__ int h[256];
    const int b = blockIdx.x, t = threadIdx.x;
    h[t] = 0;
    __syncthreads();
    const int cnt = bcur[b] - b * BCAP;
    for (int i = t; i < cnt; i += 256) {
        int dst = (int)(pairs[(size_t)b * BCAP + i] >> 32);
        atomicAdd(&h[dst & 255], 1);
    }
    __syncthreads();
    int node = b * 256 + t;
    if (node < N_NODES) counts[node] = h[t];
}

__global__ __launch_bounds__(256) void bucketB2_kernel(const ll_t* __restrict__ pairs,
                                                       const int* __restrict__ bcur,
                                                       const int* __restrict__ offs,
                                                       int* __restrict__ csr) {
    __shared__ int cur[256];
    const int b = blockIdx.x, t = threadIdx.x;
    int node = b * 256 + t;
    cur[t] = (node < N_NODES) ? offs[node] : 0;
    __syncthreads();
    const int cnt = bcur[b] - b * BCAP;
    for (int i = t; i < cnt; i += 256) {
        ll_t p = pairs[(size_t)b * BCAP + i];
        int src = (int)(p & 0xffffffff);
        int dst = (int)(p >> 32);
        int pos = atomicAdd(&cur[dst & 255], 1);
        csr[pos] = src;
    }
}

// ---------------------------------------------------------------------------
// counts -> offs scans
// ---------------------------------------------------------------------------
__global__ __launch_bounds__(256) void block_sum_kernel(const int* __restrict__ counts,
                                                        int* __restrict__ blockSums, int n) {
    int b = blockIdx.x, t = threadIdx.x;
    int base = b * 1024 + t * 4;
    int s = 0;
    if (base + 3 < n) {
        int4 v = *reinterpret_cast<const int4*>(counts + base);
        s = v.x + v.y + v.z + v.w;
    } else {
        for (int i = 0; i < 4; i++) if (base + i < n) s += counts[base + i];
    }
    #pragma unroll
    for (int off = 32; off > 0; off >>= 1) s += __shfl_down(s, off);
    __shared__ int wsum[4];
    int lane = t & 63, wv = t >> 6;
    if (lane == 0) wsum[wv] = s;
    __syncthreads();
    if (t == 0) blockSums[b] = wsum[0] + wsum[1] + wsum[2] + wsum[3];
}

__global__ __launch_bounds__(256) void scan_sums_kernel(const int* __restrict__ blockSums,
                                                        int* __restrict__ blockBase, int nb) {
    __shared__ int sh[256];
    int t = threadIdx.x;
    int v = (t < nb) ? blockSums[t] : 0;
    sh[t] = v;
    __syncthreads();
    for (int off = 1; off < 256; off <<= 1) {
        int u = (t >= off) ? sh[t - off] : 0;
        __syncthreads();
        sh[t] += u;
        __syncthreads();
    }
    if (t < nb) blockBase[t] = sh[t] - v;
}

__global__ __launch_bounds__(256) void scan_final_kernel(const int* __restrict__ counts,
                                                         const int* __restrict__ blockBase,
                                                         int* __restrict__ offsets, int n) {
    int b = blockIdx.x, t = threadIdx.x;
    int base = b * 1024 + t * 4;
    int c[4] = {0, 0, 0, 0};
    if (base + 3 < n) {
        int4 v = *reinterpret_cast<const int4*>(counts + base);
        c[0] = v.x; c[1] = v.y; c[2] = v.z; c[3] = v.w;
    } else {
        for (int i = 0; i < 4; i++) if (base + i < n) c[i] = counts[base + i];
    }
    int tsum = c[0] + c[1] + c[2] + c[3];
    int x = tsum;
    int lane = t & 63, wv = t >> 6;
    #pragma unroll
    for (int off = 1; off < 64; off <<= 1) {
        int u = __shfl_up(x, off);
        if (lane >= off) x += u;
    }
    __shared__ int wsum[4];
    if (lane == 63) wsum[wv] = x;
    __syncthreads();
    int wbase = 0;
    for (int w = 0; w < wv; w++) wbase += wsum[w];
    int run = blockBase[b] + wbase + (x - tsum);
    for (int i = 0; i < 4; i++) {
        if (base + i < n) { offsets[base + i] = run; run += c[i]; }
    }
    if (b == 0 && t == 0) offsets[n] = ETOT;
}

// ---------------------------------------------------------------------------
// MFMA GEMM with FUSED attention-logit epilogue.
// ---------------------------------------------------------------------------
template <int OUT, int H, bool IN_BF16>
__global__ __launch_bounds__(256) void gemm_mfma(const void* __restrict__ Xv,
                                                 const float* __restrict__ W,
                                                 const float* __restrict__ a_s,
                                                 const float* __restrict__ a_d,
                                                 ushort_t* __restrict__ Hout,
                                                 float* __restrict__ alS,
                                                 float* __restrict__ alD, int nrows) {
    constexpr int NB  = OUT / 16;
    constexpr int CPH = OUT / H;
    constexpr int TPH = NB / H;
    __shared__ ushort_t Wt[OUT * 128];
    const int t = threadIdx.x;

    {
        constexpr int GROUPS = 256 / OUT;
        constexpr int KPG    = 128 / GROUPS;
        int col = t & (OUT - 1);
        int kb0 = (t / OUT) * KPG;
        for (int c = 0; c < KPG / 8; c++) {
            int kb = kb0 + c * 8;
            short8 v;
            #pragma unroll
            for (int j = 0; j < 8; j++) v[j] = (short)f2bf(W[(kb + j) * OUT + col]);
            int off = col * 256 + (((kb >> 3) << 4) ^ ((col & 15) << 4));
            *reinterpret_cast<short8*>(reinterpret_cast<char*>(Wt) + off) = v;
        }
    }
    __syncthreads();

    const int wv = t >> 6, lane = t & 63;
    const int rowBase = (blockIdx.x * 4 + wv) * 32;
    if (rowBase >= nrows) return;
    const int r0 = lane & 15, g = lane >> 4;

    f32x4 acc[2][NB];
    #pragma unroll
    for (int rt = 0; rt < 2; rt++)
        #pragma unroll
        for (int nb = 0; nb < NB; nb++) acc[rt][nb] = {0.f, 0.f, 0.f, 0.f};

    #pragma unroll
    for (int step = 0; step < 4; step++) {
        short8 a0, a1;
        if (IN_BF16) {
            const ushort_t* X = (const ushort_t*)Xv;
            a0 = *reinterpret_cast<const short8*>(X + (size_t)(rowBase + r0) * 128 + step * 32 + g * 8);
            a1 = *reinterpret_cast<const short8*>(X + (size_t)(rowBase + 16 + r0) * 128 + step * 32 + g * 8);
        } else {
            const float* X = (const float*)Xv;
            const float* p0 = X + (size_t)(rowBase + r0) * 128 + step * 32 + g * 8;
            const float* p1 = X + (size_t)(rowBase + 16 + r0) * 128 + step * 32 + g * 8;
            #pragma unroll
            for (int j = 0; j < 8; j++) { a0[j] = (short)f2bf(p0[j]); a1[j] = (short)f2bf(p1[j]); }
        }
        const int chunkoff = (step << 6) + (g << 4);
        #pragma unroll
        for (int nb = 0; nb < NB; nb++) {
            int col = nb * 16 + r0;
            int off = col * 256 + (chunkoff ^ (r0 << 4));
            short8 b = *reinterpret_cast<const short8*>(reinterpret_cast<const char*>(Wt) + off);
            acc[0][nb] = __builtin_amdgcn_mfma_f32_16x16x32_bf16(a0, b, acc[0][nb], 0, 0, 0);
            acc[1][nb] = __builtin_amdgcn_mfma_f32_16x16x32_bf16(a1, b, acc[1][nb], 0, 0, 0);
        }
    }

    #pragma unroll
    for (int rt = 0; rt < 2; rt++) {
        #pragma unroll
        for (int nb = 0; nb < NB; nb++) {
            #pragma unroll
            for (int rr = 0; rr < 4; rr++) {
                int row = rowBase + rt * 16 + g * 4 + rr;
                Hout[(size_t)row * OUT + nb * 16 + r0] = f2bf(acc[rt][nb][rr]);
            }
        }
    }

    float asv[NB], adv[NB];
    #pragma unroll
    for (int nb = 0; nb < NB; nb++) {
        int col = nb * 16 + r0;
        int h = col / CPH, c = col % CPH;
        asv[nb] = a_s[h * CPH + c];
        adv[nb] = a_d[h * CPH + c];
    }
    #pragma unroll
    for (int rt = 0; rt < 2; rt++) {
        #pragma unroll
        for (int rr = 0; rr < 4; rr++) {
            int row = rowBase + rt * 16 + g * 4 + rr;
            #pragma unroll
            for (int h = 0; h < H; h++) {
                float vs = 0.f, vd = 0.f;
                #pragma unroll
                for (int tt = 0; tt < TPH; tt++) {
                    int nb = h * TPH + tt;
                    vs += acc[rt][nb][rr] * asv[nb];
                    vd += acc[rt][nb][rr] * adv[nb];
                }
                #pragma unroll
                for (int off = 8; off > 0; off >>= 1) {
                    vs += __shfl_xor(vs, off, 16);
                    vd += __shfl_xor(vd, off, 16);
                }
                if (r0 == 0) {
                    alS[row * H + h] = vs;
                    alD[row * H + h] = vd;
                }
            }
        }
    }
}

// ---------------------------------------------------------------------------
// Single-pass aggregation, CT=128 (4 heads), UNSHIFTED softmax:
// w = exp(leaky(alS[s,h]+alD[n,h])); acc += w*h; d += w (identical across the
// head group's lanes). o = acc/d. Mathematically identical to max-shifted
// (ratio invariant); range safe: |e| << 88.
// ---------------------------------------------------------------------------
template <bool DO_ELU>
__global__ __launch_bounds__(256) void agg128_sp(const ushort_t* __restrict__ Hf,
                                                 const float* __restrict__ alS,
                                                 const float* __restrict__ alD,
                                                 const float* __restrict__ bias,
                                                 const int* __restrict__ offs,
                                                 const int* __restrict__ csr,
                                                 ushort_t* __restrict__ out, int n) {
    int wave = (blockIdx.x * blockDim.x + threadIdx.x) >> 6;
    int lane = threadIdx.x & 63;
    if (wave >= n) return;
    const int node = wave;
    const int s0 = offs[node], s1 = offs[node + 1];
    const int hh = lane >> 4;
    const float aldn = alD[node * 4 + hh];

    float acc0 = 0.f, acc1 = 0.f, dacc = 0.f;

    int i = s0;
    for (; i + 3 < s1; i += 4) {
        int sa = csr[i], sb = csr[i + 1], sc_ = csr[i + 2], sd = csr[i + 3];
        float ea = alS[sa * 4 + hh], eb = alS[sb * 4 + hh];
        float ec = alS[sc_ * 4 + hh], ed = alS[sd * 4 + hh];
        uint_t va = *reinterpret_cast<const uint_t*>(Hf + (size_t)sa * 128 + lane * 2);
        uint_t vb = *reinterpret_cast<const uint_t*>(Hf + (size_t)sb * 128 + lane * 2);
        uint_t vc = *reinterpret_cast<const uint_t*>(Hf + (size_t)sc_ * 128 + lane * 2);
        uint_t vd = *reinterpret_cast<const uint_t*>(Hf + (size_t)sd * 128 + lane * 2);
        ea += aldn; ea = (ea > 0.f) ? ea : NEG_SLOPE * ea; float wa = __expf(ea);
        eb += aldn; eb = (eb > 0.f) ? eb : NEG_SLOPE * eb; float wb = __expf(eb);
        ec += aldn; ec = (ec > 0.f) ? ec : NEG_SLOPE * ec; float wc = __expf(ec);
        ed += aldn; ed = (ed > 0.f) ? ed : NEG_SLOPE * ed; float wd = __expf(ed);
        acc0 += wa * bf2f_lo(va); acc1 += wa * bf2f_hi(va);
        acc0 += wb * bf2f_lo(vb); acc1 += wb * bf2f_hi(vb);
        acc0 += wc * bf2f_lo(vc); acc1 += wc * bf2f_hi(vc);
        acc0 += wd * bf2f_lo(vd); acc1 += wd * bf2f_hi(vd);
        dacc += (wa + wb) + (wc + wd);
    }
    for (; i < s1; i++) {
        int sa = csr[i];
        float ea = alS[sa * 4 + hh];
        uint_t va = *reinterpret_cast<const uint_t*>(Hf + (size_t)sa * 128 + lane * 2);
        ea += aldn; ea = (ea > 0.f) ? ea : NEG_SLOPE * ea; float wa = __expf(ea);
        acc0 += wa * bf2f_lo(va); acc1 += wa * bf2f_hi(va);
        dacc += wa;
    }

    float rd = 1.0f / dacc;
    float o0 = acc0 * rd + bias[2 * lane];
    float o1 = acc1 * rd + bias[2 * lane + 1];
    if (DO_ELU) {
        o0 = (o0 > 0.0f) ? o0 : expm1f(o0);
        o1 = (o1 > 0.0f) ? o1 : expm1f(o1);
    }
    uint_t packed = (uint_t)f2bf(o0) | ((uint_t)f2bf(o1) << 16);
    *reinterpret_cast<uint_t*>(out + (size_t)node * 128 + lane * 2) = packed;
}

// ---------------------------------------------------------------------------
// Single-pass aggregation, CT=64 single head, fp32 output, UNSHIFTED softmax.
// Half-wave per edge: 32 lanes x uint (2 ch); halves' partial (acc,d) combine
// via shfl_xor(32).
// ---------------------------------------------------------------------------
__global__ __launch_bounds__(256) void agg64_sp(const ushort_t* __restrict__ Hf,
                                                const float* __restrict__ alS,
                                                const float* __restrict__ alD,
                                                const float* __restrict__ bias,
                                                const int* __restrict__ offs,
                                                const int* __restrict__ csr,
                                                float* __restrict__ out, int n) {
    int wave = (blockIdx.x * blockDim.x + threadIdx.x) >> 6;
    int lane = threadIdx.x & 63;
    if (wave >= n) return;
    const int node = wave;
    const int s0 = offs[node], s1 = offs[node + 1];
    const float aldn = alD[node];

    const int eh = lane >> 5;        // which edge of the pair
    const int c2 = lane & 31;        // uint index (channels 2*c2, 2*c2+1)
    float acc0 = 0.f, acc1 = 0.f, dacc = 0.f;

    int i = s0;
    for (; i + 3 < s1; i += 4) {
        int sa = csr[i + eh];
        int sb = csr[i + 2 + eh];
        float ea = alS[sa], eb = alS[sb];
        uint_t va = *reinterpret_cast<const uint_t*>(Hf + (size_t)sa * 64 + c2 * 2);
        uint_t vb = *reinterpret_cast<const uint_t*>(Hf + (size_t)sb * 64 + c2 * 2);
        ea += aldn; ea = (ea > 0.f) ? ea : NEG_SLOPE * ea; float wa = __expf(ea);
        eb += aldn; eb = (eb > 0.f) ? eb : NEG_SLOPE * eb; float wb = __expf(eb);
        acc0 += wa * bf2f_lo(va); acc1 += wa * bf2f_hi(va);
        acc0 += wb * bf2f_lo(vb); acc1 += wb * bf2f_hi(vb);
        dacc += wa + wb;
    }
    for (; i < s1; i += 2) {
        int idx = i + eh;
        if (idx < s1) {
            int sa = csr[idx];
            float ea = alS[sa];
            uint_t va = *reinterpret_cast<const uint_t*>(Hf + (size_t)sa * 64 + c2 * 2);
            ea += aldn; ea = (ea > 0.f) ? ea : NEG_SLOPE * ea; float wa = __expf(ea);
            acc0 += wa * bf2f_lo(va); acc1 += wa * bf2f_hi(va);
            dacc += wa;
        }
    }

    acc0 += __shfl_xor(acc0, 32);
    acc1 += __shfl_xor(acc1, 32);
    dacc += __shfl_xor(dacc, 32);
    if (lane < 32) {
        float rd = 1.0f / dacc;
        float2 o;
        o.x = acc0 * rd + bias[2 * c2];
        o.y = acc1 * rd + bias[2 * c2 + 1];
        *reinterpret_cast<float2*>(out + (size_t)node * 64 + c2 * 2) = o;
    }
}

// ---------------------------------------------------------------------------
extern "C" void kernel_launch(void* const* d_in, const int* in_sizes, int n_in,
                              void* d_out, int out_size, void* d_ws, size_t ws_size,
                              hipStream_t stream) {
    const float* x   = (const float*)d_in[0];
    const int*   ei  = (const int*)d_in[1];
    const float* W0  = (const float*)d_in[2];
    const float* as0 = (const float*)d_in[3];
    const float* ad0 = (const float*)d_in[4];
    const float* b0  = (const float*)d_in[5];
    const float* W1  = (const float*)d_in[6];
    const float* as1 = (const float*)d_in[7];
    const float* ad1 = (const float*)d_in[8];
    const float* b1  = (const float*)d_in[9];
    const float* W2  = (const float*)d_in[10];
    const float* as2 = (const float*)d_in[11];
    const float* ad2 = (const float*)d_in[12];
    const float* b2  = (const float*)d_in[13];

    char* ws = (char*)d_ws;
    size_t off = 0;
    auto alloc = [&](size_t bytes) -> void* {
        void* p = ws + off;
        off += (bytes + 255) & ~size_t(255);
        return p;
    };
    ushort_t* B0   = (ushort_t*)alloc((size_t)N_NODES * 128 * sizeof(ushort_t));
    ushort_t* B1   = (ushort_t*)alloc((size_t)N_NODES * 128 * sizeof(ushort_t));
    float* alS     = (float*)alloc((size_t)N_NODES * 4 * sizeof(float));
    float* alD     = (float*)alloc((size_t)N_NODES * 4 * sizeof(float));
    int*   counts  = (int*)alloc((size_t)N_NODES * sizeof(int));
    int*   offs    = (int*)alloc((size_t)(N_NODES + 1) * sizeof(int));
    int*   csr     = (int*)alloc((size_t)ETOT * sizeof(int));
    int*   bsums   = (int*)alloc(256 * sizeof(int));
    int*   bbase   = (int*)alloc(256 * sizeof(int));
    int*   bcur    = (int*)alloc((size_t)NBUCK * sizeof(int));
    ll_t*  pairs   = (ll_t*)alloc((size_t)NBUCK * BCAP * sizeof(ll_t));

    const int NB = (N_NODES + 1023) / 1024;

    // ---- CSR build (bucketed) ----
    binit_kernel<<<(NBUCK + 255) / 256, 256, 0, stream>>>(bcur);
    bucketA_kernel<<<(ETOT + EPB_A - 1) / EPB_A, 256, 0, stream>>>(ei, bcur, pairs);
    bucketB1_kernel<<<NBUCK, 256, 0, stream>>>(pairs, bcur, counts);
    block_sum_kernel<<<NB, 256, 0, stream>>>(counts, bsums, N_NODES);
    scan_sums_kernel<<<1, 256, 0, stream>>>(bsums, bbase, NB);
    scan_final_kernel<<<NB, 256, 0, stream>>>(counts, bbase, offs, N_NODES);
    bucketB2_kernel<<<NBUCK, 256, 0, stream>>>(pairs, bcur, offs, csr);

    const int GEMM_GRID = (N_NODES / 32 + 3) / 4;
    const int NODE_WAVE_GRID = (N_NODES + 3) / 4;

    // ---- layer 0: fp32 x -> bf16 h (al fused into GEMM epilogue) ----
    gemm_mfma<128, 4, false><<<GEMM_GRID, 256, 0, stream>>>(x, W0, as0, ad0, B0, alS, alD, N_NODES);
    agg128_sp<true><<<NODE_WAVE_GRID, 256, 0, stream>>>(B0, alS, alD, b0, offs, csr, B1, N_NODES);

    // ---- layer 1 ----
    gemm_mfma<128, 4, true><<<GEMM_GRID, 256, 0, stream>>>(B1, W1, as1, ad1, B0, alS, alD, N_NODES);
    agg128_sp<true><<<NODE_WAVE_GRID, 256, 0, stream>>>(B0, alS, alD, b1, offs, csr, B1, N_NODES);

    // ---- layer 2: OUT=64, single head, fp32 out ----
    gemm_mfma<64, 1, true><<<GEMM_GRID, 256, 0, stream>>>(B1, W2, as2, ad2, B0, alS, alD, N_NODES);
    agg64_sp<<<NODE_WAVE_GRID, 256, 0, stream>>>(B0, alS, alD, b2, offs, csr,
                                                 (float*)d_out, N_NODES);
}

// Round 10
// 391.031 us; speedup vs baseline: 2.3870x; 1.0196x over previous
//
#include <hip/hip_runtime.h>
#include <hip/hip_bf16.h>
#include <math.h>

#define N_NODES 100000
#define N_EDGES 1000000
#define ETOT    (N_EDGES + N_NODES)

#define NBUCK 391          // ceil(N_NODES/256): 256 nodes per bucket
#define BCAP  3584         // bucket capacity (mean 2813, ~15 sigma margin)
#define EPB_A 4096         // edges per phase-A block

constexpr float NEG_SLOPE = 0.2f;
constexpr float LOG2E = 1.4426950408889634f;

typedef short short8 __attribute__((ext_vector_type(8)));
typedef float f32x4  __attribute__((ext_vector_type(4)));
typedef unsigned short ushort_t;
typedef unsigned int uint_t;

__device__ __forceinline__ ushort_t f2bf(float f) {
    uint_t u = __float_as_uint(f);
    u += 0x7fff + ((u >> 16) & 1);          // RNE (finite values only)
    return (ushort_t)(u >> 16);
}
__device__ __forceinline__ float bf2f_lo(uint_t v) { return __uint_as_float(v << 16); }
__device__ __forceinline__ float bf2f_hi(uint_t v) { return __uint_as_float(v & 0xffff0000u); }

__device__ __forceinline__ float exp2_fast(float x) {
#if __has_builtin(__builtin_amdgcn_exp2f)
    return __builtin_amdgcn_exp2f(x);
#else
    return exp2f(x);
#endif
}

// ---------------------------------------------------------------------------
// CSR build, bucketed. pairs packed: (src << 8) | (dst & 255)  [src<2^17]
// ---------------------------------------------------------------------------
__global__ void binit_kernel(int* __restrict__ bcur) {
    int b = blockIdx.x * blockDim.x + threadIdx.x;
    if (b < NBUCK) bcur[b] = b * BCAP;
}

__global__ __launch_bounds__(256) void bucketA_kernel(const int* __restrict__ ei,
                                                      int* __restrict__ bcur,
                                                      uint_t* __restrict__ pairs) {
    __shared__ uint_t spair[EPB_A];
    __shared__ int  sgpos[EPB_A];
    __shared__ int  hist[NBUCK];
    __shared__ int  hscan[NBUCK];
    __shared__ int  base[NBUCK];
    __shared__ int  cur2[NBUCK];
    __shared__ int  sc[512];

    const int t = threadIdx.x;
    const int e0 = blockIdx.x * EPB_A;
    const int nvalid = min(EPB_A, ETOT - e0);

    for (int b = t; b < NBUCK; b += 256) { hist[b] = 0; cur2[b] = 0; }
    __syncthreads();

    for (int r = 0; r < EPB_A / 256; r++) {
        int i = e0 + r * 256 + t;
        if (i < ETOT) {
            int dst = (i < N_EDGES) ? ei[N_EDGES + i] : (i - N_EDGES);
            atomicAdd(&hist[dst >> 8], 1);
        }
    }
    __syncthreads();

    sc[t]       = (t < NBUCK) ? hist[t] : 0;
    sc[t + 256] = (t + 256 < NBUCK) ? hist[t + 256] : 0;
    __syncthreads();
    for (int off = 1; off < 512; off <<= 1) {
        int v0 = (t >= off) ? sc[t - off] : 0;
        int v1 = sc[t + 256 - off];
        __syncthreads();
        sc[t] += v0;
        sc[t + 256] += v1;
        __syncthreads();
    }
    for (int b = t; b < NBUCK; b += 256) {
        hscan[b] = sc[b] - hist[b];
        if (hist[b] > 0) base[b] = atomicAdd(&bcur[b], hist[b]);
    }
    __syncthreads();

    for (int r = 0; r < EPB_A / 256; r++) {
        int i = e0 + r * 256 + t;
        if (i < ETOT) {
            int src, dst;
            if (i < N_EDGES) { src = ei[i]; dst = ei[N_EDGES + i]; }
            else             { src = dst = i - N_EDGES; }
            int b = dst >> 8;
            int lr = atomicAdd(&cur2[b], 1);
            int slot = hscan[b] + lr;
            spair[slot] = ((uint_t)src << 8) | (uint_t)(dst & 255);
            sgpos[slot] = base[b] + lr;
        }
    }
    __syncthreads();

    for (int s = t; s < nvalid; s += 256)
        pairs[sgpos[s]] = spair[s];
}

// B1: per-bucket histogram + LOCAL exclusive scan -> localoff[node], btot[b]
__global__ __launch_bounds__(256) void bucketB1_kernel(const uint_t* __restrict__ pairs,
                                                       const int* __restrict__ bcur,
                                                       int* __restrict__ localoff,
                                                       int* __restrict__ btot) {
    __shared__ int h[256];
    __shared__ int ws[4];
    const int b = blockIdx.x, t = threadIdx.x;
    h[t] = 0;
    __syncthreads();
    const int cnt = bcur[b] - b * BCAP;
    for (int i = t; i < cnt; i += 256)
        atomicAdd(&h[pairs[b * BCAP + i] & 255u], 1);
    __syncthreads();
    int c = h[t];
    int lane = t & 63, wv = t >> 6;
    int x = c;
    #pragma unroll
    for (int off = 1; off < 64; off <<= 1) {
        int u = __shfl_up(x, off);
        if (lane >= off) x += u;
    }
    if (lane == 63) ws[wv] = x;
    __syncthreads();
    int wb = 0;
    for (int w = 0; w < wv; w++) wb += ws[w];
    localoff[b * 256 + t] = wb + x - c;
    if (t == 255) btot[b] = wb + x;
}

// scan 391 bucket totals -> exclusive bucketBase; also writes offs[N]=ETOT
__global__ __launch_bounds__(256) void scanB_kernel(const int* __restrict__ btot,
                                                    int* __restrict__ bbase,
                                                    int* __restrict__ offs) {
    __shared__ int sc[512];
    int t = threadIdx.x;
    int v0 = (t < NBUCK) ? btot[t] : 0;
    int v1 = (t + 256 < NBUCK) ? btot[t + 256] : 0;
    sc[t] = v0; sc[t + 256] = v1;
    __syncthreads();
    for (int off = 1; off < 512; off <<= 1) {
        int u0 = (t >= off) ? sc[t - off] : 0;
        int u1 = sc[t + 256 - off];
        __syncthreads();
        sc[t] += u0;
        sc[t + 256] += u1;
        __syncthreads();
    }
    if (t < NBUCK) bbase[t] = sc[t] - v0;
    if (t + 256 < NBUCK) bbase[t + 256] = sc[t + 256] - v1;
    if (t == 0) offs[N_NODES] = ETOT;
}

// B2: write offs[node] = bbase[b]+localoff, scatter csr within bucket window
__global__ __launch_bounds__(256) void bucketB2_kernel(const uint_t* __restrict__ pairs,
                                                       const int* __restrict__ bcur,
                                                       const int* __restrict__ localoff,
                                                       const int* __restrict__ bbase,
                                                       int* __restrict__ offs,
                                                       int* __restrict__ csr) {
    __shared__ int cur[256];
    const int b = blockIdx.x, t = threadIdx.x;
    const int node = b * 256 + t;
    const int my = bbase[b] + localoff[b * 256 + t];
    cur[t] = my;
    if (node < N_NODES) offs[node] = my;
    __syncthreads();
    const int cnt = bcur[b] - b * BCAP;
    for (int i = t; i < cnt; i += 256) {
        uint_t p = pairs[b * BCAP + i];
        int pos = atomicAdd(&cur[p & 255u], 1);
        csr[pos] = (int)(p >> 8);
    }
}

// ---------------------------------------------------------------------------
// MFMA GEMM with FUSED attention-logit epilogue (logits pre-scaled by log2e).
// ---------------------------------------------------------------------------
template <int OUT, int H, bool IN_BF16>
__global__ __launch_bounds__(256) void gemm_mfma(const void* __restrict__ Xv,
                                                 const float* __restrict__ W,
                                                 const float* __restrict__ a_s,
                                                 const float* __restrict__ a_d,
                                                 ushort_t* __restrict__ Hout,
                                                 float* __restrict__ alS,
                                                 float* __restrict__ alD, int nrows) {
    constexpr int NB  = OUT / 16;
    constexpr int CPH = OUT / H;
    constexpr int TPH = NB / H;
    __shared__ ushort_t Wt[OUT * 128];
    const int t = threadIdx.x;

    {
        constexpr int GROUPS = 256 / OUT;
        constexpr int KPG    = 128 / GROUPS;
        int col = t & (OUT - 1);
        int kb0 = (t / OUT) * KPG;
        for (int c = 0; c < KPG / 8; c++) {
            int kb = kb0 + c * 8;
            short8 v;
            #pragma unroll
            for (int j = 0; j < 8; j++) v[j] = (short)f2bf(W[(kb + j) * OUT + col]);
            int off = col * 256 + (((kb >> 3) << 4) ^ ((col & 15) << 4));
            *reinterpret_cast<short8*>(reinterpret_cast<char*>(Wt) + off) = v;
        }
    }
    __syncthreads();

    const int wv = t >> 6, lane = t & 63;
    const int rowBase = (blockIdx.x * 4 + wv) * 32;
    if (rowBase >= nrows) return;
    const int r0 = lane & 15, g = lane >> 4;

    f32x4 acc[2][NB];
    #pragma unroll
    for (int rt = 0; rt < 2; rt++)
        #pragma unroll
        for (int nb = 0; nb < NB; nb++) acc[rt][nb] = {0.f, 0.f, 0.f, 0.f};

    #pragma unroll
    for (int step = 0; step < 4; step++) {
        short8 a0, a1;
        if (IN_BF16) {
            const ushort_t* X = (const ushort_t*)Xv;
            a0 = *reinterpret_cast<const short8*>(X + (size_t)(rowBase + r0) * 128 + step * 32 + g * 8);
            a1 = *reinterpret_cast<const short8*>(X + (size_t)(rowBase + 16 + r0) * 128 + step * 32 + g * 8);
        } else {
            const float* X = (const float*)Xv;
            const float* p0 = X + (size_t)(rowBase + r0) * 128 + step * 32 + g * 8;
            const float* p1 = X + (size_t)(rowBase + 16 + r0) * 128 + step * 32 + g * 8;
            #pragma unroll
            for (int j = 0; j < 8; j++) { a0[j] = (short)f2bf(p0[j]); a1[j] = (short)f2bf(p1[j]); }
        }
        const int chunkoff = (step << 6) + (g << 4);
        #pragma unroll
        for (int nb = 0; nb < NB; nb++) {
            int col = nb * 16 + r0;
            int off = col * 256 + (chunkoff ^ (r0 << 4));
            short8 b = *reinterpret_cast<const short8*>(reinterpret_cast<const char*>(Wt) + off);
            acc[0][nb] = __builtin_amdgcn_mfma_f32_16x16x32_bf16(a0, b, acc[0][nb], 0, 0, 0);
            acc[1][nb] = __builtin_amdgcn_mfma_f32_16x16x32_bf16(a1, b, acc[1][nb], 0, 0, 0);
        }
    }

    #pragma unroll
    for (int rt = 0; rt < 2; rt++) {
        #pragma unroll
        for (int nb = 0; nb < NB; nb++) {
            #pragma unroll
            for (int rr = 0; rr < 4; rr++) {
                int row = rowBase + rt * 16 + g * 4 + rr;
                Hout[(size_t)row * OUT + nb * 16 + r0] = f2bf(acc[rt][nb][rr]);
            }
        }
    }

    float asv[NB], adv[NB];
    #pragma unroll
    for (int nb = 0; nb < NB; nb++) {
        int col = nb * 16 + r0;
        int h = col / CPH, c = col % CPH;
        asv[nb] = a_s[h * CPH + c];
        adv[nb] = a_d[h * CPH + c];
    }
    #pragma unroll
    for (int rt = 0; rt < 2; rt++) {
        #pragma unroll
        for (int rr = 0; rr < 4; rr++) {
            int row = rowBase + rt * 16 + g * 4 + rr;
            #pragma unroll
            for (int h = 0; h < H; h++) {
                float vs = 0.f, vd = 0.f;
                #pragma unroll
                for (int tt = 0; tt < TPH; tt++) {
                    int nb = h * TPH + tt;
                    vs += acc[rt][nb][rr] * asv[nb];
                    vd += acc[rt][nb][rr] * adv[nb];
                }
                #pragma unroll
                for (int off = 8; off > 0; off >>= 1) {
                    vs += __shfl_xor(vs, off, 16);
                    vd += __shfl_xor(vd, off, 16);
                }
                if (r0 == 0) {
                    alS[row * H + h] = vs * LOG2E;   // pre-scaled for exp2
                    alD[row * H + h] = vd * LOG2E;
                }
            }
        }
    }
}

// ---------------------------------------------------------------------------
// Single-pass aggregation, CT=128 (4 heads), unshifted softmax in exp2 domain.
// w = exp2(max(e, 0.2e)), e = alS'[s,h]+alD'[n,h] (pre-scaled by log2e).
// 32-bit indexing; row stride = 64 uints (128 bf16).
// ---------------------------------------------------------------------------
template <bool DO_ELU>
__global__ __launch_bounds__(256) void agg128_sp(const ushort_t* __restrict__ Hf,
                                                 const float* __restrict__ alS,
                                                 const float* __restrict__ alD,
                                                 const float* __restrict__ bias,
                                                 const int* __restrict__ offs,
                                                 const int* __restrict__ csr,
                                                 ushort_t* __restrict__ out, int n) {
    int wave = (blockIdx.x * blockDim.x + threadIdx.x) >> 6;
    int lane = threadIdx.x & 63;
    if (wave >= n) return;
    const int node = wave;
    const int s0 = offs[node], s1 = offs[node + 1];
    const int hh = lane >> 4;
    const float aldn = alD[node * 4 + hh];
    const uint_t* __restrict__ Hf32 = (const uint_t*)Hf;

    float acc0 = 0.f, acc1 = 0.f, dacc = 0.f;

    int i = s0;
    for (; i + 3 < s1; i += 4) {
        int sa = csr[i], sb = csr[i + 1], sc_ = csr[i + 2], sd = csr[i + 3];
        float ea = alS[sa * 4 + hh], eb = alS[sb * 4 + hh];
        float ec = alS[sc_ * 4 + hh], ed = alS[sd * 4 + hh];
        uint_t va = Hf32[sa * 64 + lane];
        uint_t vb = Hf32[sb * 64 + lane];
        uint_t vc = Hf32[sc_ * 64 + lane];
        uint_t vd = Hf32[sd * 64 + lane];
        ea += aldn; float wa = exp2_fast(fmaxf(ea, NEG_SLOPE * ea));
        eb += aldn; float wb = exp2_fast(fmaxf(eb, NEG_SLOPE * eb));
        ec += aldn; float wc = exp2_fast(fmaxf(ec, NEG_SLOPE * ec));
        ed += aldn; float wd = exp2_fast(fmaxf(ed, NEG_SLOPE * ed));
        acc0 += wa * bf2f_lo(va); acc1 += wa * bf2f_hi(va);
        acc0 += wb * bf2f_lo(vb); acc1 += wb * bf2f_hi(vb);
        acc0 += wc * bf2f_lo(vc); acc1 += wc * bf2f_hi(vc);
        acc0 += wd * bf2f_lo(vd); acc1 += wd * bf2f_hi(vd);
        dacc += (wa + wb) + (wc + wd);
    }
    for (; i < s1; i++) {
        int sa = csr[i];
        float ea = alS[sa * 4 + hh];
        uint_t va = Hf32[sa * 64 + lane];
        ea += aldn; float wa = exp2_fast(fmaxf(ea, NEG_SLOPE * ea));
        acc0 += wa * bf2f_lo(va); acc1 += wa * bf2f_hi(va);
        dacc += wa;
    }

    float rd = 1.0f / dacc;
    float2 bv = *reinterpret_cast<const float2*>(bias + 2 * lane);
    float o0 = acc0 * rd + bv.x;
    float o1 = acc1 * rd + bv.y;
    if (DO_ELU) {
        o0 = (o0 > 0.0f) ? o0 : expm1f(o0);
        o1 = (o1 > 0.0f) ? o1 : expm1f(o1);
    }
    uint_t packed = (uint_t)f2bf(o0) | ((uint_t)f2bf(o1) << 16);
    *reinterpret_cast<uint_t*>(out + node * 128 + lane * 2) = packed;
}

// ---------------------------------------------------------------------------
// Single-pass aggregation, CT=64 single head, fp32 output, half-wave per edge.
// Row stride = 32 uints (64 bf16).
// ---------------------------------------------------------------------------
__global__ __launch_bounds__(256) void agg64_sp(const ushort_t* __restrict__ Hf,
                                                const float* __restrict__ alS,
                                                const float* __restrict__ alD,
                                                const float* __restrict__ bias,
                                                const int* __restrict__ offs,
                                                const int* __restrict__ csr,
                                                float* __restrict__ out, int n) {
    int wave = (blockIdx.x * blockDim.x + threadIdx.x) >> 6;
    int lane = threadIdx.x & 63;
    if (wave >= n) return;
    const int node = wave;
    const int s0 = offs[node], s1 = offs[node + 1];
    const float aldn = alD[node];
    const uint_t* __restrict__ Hf32 = (const uint_t*)Hf;

    const int eh = lane >> 5;
    const int c2 = lane & 31;
    float acc0 = 0.f, acc1 = 0.f, dacc = 0.f;

    int i = s0;
    for (; i + 3 < s1; i += 4) {
        int sa = csr[i + eh];
        int sb = csr[i + 2 + eh];
        float ea = alS[sa], eb = alS[sb];
        uint_t va = Hf32[sa * 32 + c2];
        uint_t vb = Hf32[sb * 32 + c2];
        ea += aldn; float wa = exp2_fast(fmaxf(ea, NEG_SLOPE * ea));
        eb += aldn; float wb = exp2_fast(fmaxf(eb, NEG_SLOPE * eb));
        acc0 += wa * bf2f_lo(va); acc1 += wa * bf2f_hi(va);
        acc0 += wb * bf2f_lo(vb); acc1 += wb * bf2f_hi(vb);
        dacc += wa + wb;
    }
    for (; i < s1; i += 2) {
        int idx = i + eh;
        if (idx < s1) {
            int sa = csr[idx];
            float ea = alS[sa];
            uint_t va = Hf32[sa * 32 + c2];
            ea += aldn; float wa = exp2_fast(fmaxf(ea, NEG_SLOPE * ea));
            acc0 += wa * bf2f_lo(va); acc1 += wa * bf2f_hi(va);
            dacc += wa;
        }
    }

    acc0 += __shfl_xor(acc0, 32);
    acc1 += __shfl_xor(acc1, 32);
    dacc += __shfl_xor(dacc, 32);
    if (lane < 32) {
        float rd = 1.0f / dacc;
        float2 bv = *reinterpret_cast<const float2*>(bias + 2 * c2);
        float2 o;
        o.x = acc0 * rd + bv.x;
        o.y = acc1 * rd + bv.y;
        *reinterpret_cast<float2*>(out + node * 64 + c2 * 2) = o;
    }
}

// ---------------------------------------------------------------------------
extern "C" void kernel_launch(void* const* d_in, const int* in_sizes, int n_in,
                              void* d_out, int out_size, void* d_ws, size_t ws_size,
                              hipStream_t stream) {
    const float* x   = (const float*)d_in[0];
    const int*   ei  = (const int*)d_in[1];
    const float* W0  = (const float*)d_in[2];
    const float* as0 = (const float*)d_in[3];
    const float* ad0 = (const float*)d_in[4];
    const float* b0  = (const float*)d_in[5];
    const float* W1  = (const float*)d_in[6];
    const float* as1 = (const float*)d_in[7];
    const float* ad1 = (const float*)d_in[8];
    const float* b1  = (const float*)d_in[9];
    const float* W2  = (const float*)d_in[10];
    const float* as2 = (const float*)d_in[11];
    const float* ad2 = (const float*)d_in[12];
    const float* b2  = (const float*)d_in[13];

    char* ws = (char*)d_ws;
    size_t off = 0;
    auto alloc = [&](size_t bytes) -> void* {
        void* p = ws + off;
        off += (bytes + 255) & ~size_t(255);
        return p;
    };
    ushort_t* B0   = (ushort_t*)alloc((size_t)N_NODES * 128 * sizeof(ushort_t));
    ushort_t* B1   = (ushort_t*)alloc((size_t)N_NODES * 128 * sizeof(ushort_t));
    float* alS     = (float*)alloc((size_t)N_NODES * 4 * sizeof(float));
    float* alD     = (float*)alloc((size_t)N_NODES * 4 * sizeof(float));
    int*   localoff= (int*)alloc((size_t)(NBUCK * 256) * sizeof(int));
    int*   offs    = (int*)alloc((size_t)(N_NODES + 1) * sizeof(int));
    int*   csr     = (int*)alloc((size_t)ETOT * sizeof(int));
    int*   btot    = (int*)alloc(512 * sizeof(int));
    int*   bbase   = (int*)alloc(512 * sizeof(int));
    int*   bcur    = (int*)alloc((size_t)NBUCK * sizeof(int));
    uint_t* pairs  = (uint_t*)alloc((size_t)NBUCK * BCAP * sizeof(uint_t));

    // ---- CSR build (bucketed, packed pairs, per-bucket scans) ----
    binit_kernel<<<(NBUCK + 255) / 256, 256, 0, stream>>>(bcur);
    bucketA_kernel<<<(ETOT + EPB_A - 1) / EPB_A, 256, 0, stream>>>(ei, bcur, pairs);
    bucketB1_kernel<<<NBUCK, 256, 0, stream>>>(pairs, bcur, localoff, btot);
    scanB_kernel<<<1, 256, 0, stream>>>(btot, bbase, offs);
    bucketB2_kernel<<<NBUCK, 256, 0, stream>>>(pairs, bcur, localoff, bbase, offs, csr);

    const int GEMM_GRID = (N_NODES / 32 + 3) / 4;
    const int NODE_WAVE_GRID = (N_NODES + 3) / 4;

    // ---- layer 0: fp32 x -> bf16 h (al fused into GEMM epilogue) ----
    gemm_mfma<128, 4, false><<<GEMM_GRID, 256, 0, stream>>>(x, W0, as0, ad0, B0, alS, alD, N_NODES);
    agg128_sp<true><<<NODE_WAVE_GRID, 256, 0, stream>>>(B0, alS, alD, b0, offs, csr, B1, N_NODES);

    // ---- layer 1 ----
    gemm_mfma<128, 4, true><<<GEMM_GRID, 256, 0, stream>>>(B1, W1, as1, ad1, B0, alS, alD, N_NODES);
    agg128_sp<true><<<NODE_WAVE_GRID, 256, 0, stream>>>(B0, alS, alD, b1, offs, csr, B1, N_NODES);

    // ---- layer 2: OUT=64, single head, fp32 out ----
    gemm_mfma<64, 1, true><<<GEMM_GRID, 256, 0, stream>>>(B1, W2, as2, ad2, B0, alS, alD, N_NODES);
    agg64_sp<<<NODE_WAVE_GRID, 256, 0, stream>>>(B0, alS, alD, b2, offs, csr,
                                                 (float*)d_out, N_NODES);
}